// Round 3
// baseline (659.638 us; speedup 1.0000x reference)
//
#include <hip/hip_runtime.h>
#include <hip/hip_bf16.h>
#include <cstddef>

// Problem constants
constexpr int BS = 2;
constexpr int N  = 256;
constexpr int D  = 256;   // NH_N
constexpr int E  = 128;   // NH_E
constexpr int YD = 128;   // NH_Y
constexpr float RSQRT_F = 0.17677669529663687f;  // 1/sqrt(32)

typedef __attribute__((ext_vector_type(8))) short     short8;
typedef __attribute__((ext_vector_type(4))) float     f32x4;
typedef __attribute__((ext_vector_type(4))) unsigned short u16x4;
typedef __attribute__((ext_vector_type(8))) unsigned short u16x8;

__device__ __forceinline__ unsigned short f2bf(float x) {
    unsigned u = __float_as_uint(x);
    unsigned r = (u + 0x7fffu + ((u >> 16) & 1u)) >> 16;   // RNE
    return (unsigned short)r;
}
__device__ __forceinline__ float bf2f(unsigned short h) {
    return __uint_as_float(((unsigned)h) << 16);
}
__device__ __forceinline__ f32x4 mfma16(short8 a, short8 b, f32x4 c) {
    return __builtin_amdgcn_mfma_f32_16x16x32_bf16(a, b, c, 0, 0, 0);
}

// ---------------------------------------------------------------------------
// prep: transpose + bf16-convert the three big weight matrices
// ---------------------------------------------------------------------------
__global__ void wt_kernel(const float* __restrict__ Wadd, const float* __restrict__ Wmul,
                          const float* __restrict__ W2,
                          unsigned short* __restrict__ WaddT, unsigned short* __restrict__ WmulT,
                          unsigned short* __restrict__ W2T) {
    int idx = blockIdx.x * 256 + threadIdx.x;
    int s = idx >> 15;          // 32768 per section
    int k = idx & 32767;
    if (s == 0)      { int f = k >> 7, e = k & 127; WaddT[k] = f2bf(Wadd[e * 256 + f]); }
    else if (s == 1) { int f = k >> 7, e = k & 127; WmulT[k] = f2bf(Wmul[e * 256 + f]); }
    else             { int f = k & 255, e = k >> 8; W2T[k]   = f2bf(W2[f * 128 + e]); }
}

// ---------------------------------------------------------------------------
// K1: Q = x@qw+qb (fp32, row-major); K/V -> kvT bf16 transposed interleaved:
// kvT u16 layout: (( b*256 + f )*256 + j)*2 + {0:K,1:V}
// grid: 3*64, block 256
// ---------------------------------------------------------------------------
__global__ void qkv_kernel(const float* __restrict__ x,
                           const float* __restrict__ qw, const float* __restrict__ qb,
                           const float* __restrict__ kw, const float* __restrict__ kb,
                           const float* __restrict__ vw, const float* __restrict__ vb,
                           float* __restrict__ Q, unsigned short* __restrict__ kvT) {
    const int m  = blockIdx.x >> 6;
    const int rg = blockIdx.x & 63;
    const float* W = (m == 0) ? qw : (m == 1) ? kw : vw;
    const float* B = (m == 0) ? qb : (m == 1) ? kb : vb;

    __shared__ float xs[8][D];
    const int tid = threadIdx.x;
#pragma unroll
    for (int r = 0; r < 8; ++r)
        xs[r][tid] = x[(size_t)(rg * 8 + r) * D + tid];
    __syncthreads();

    float acc[8];
    const float bb = B[tid];
#pragma unroll
    for (int r = 0; r < 8; ++r) acc[r] = bb;
    for (int k = 0; k < D; ++k) {
        const float w = W[k * D + tid];
#pragma unroll
        for (int r = 0; r < 8; ++r) acc[r] += xs[r][k] * w;
    }
#pragma unroll
    for (int r = 0; r < 8; ++r) {
        const int row = rg * 8 + r;
        if (m == 0) Q[(size_t)row * D + tid] = acc[r];
        else {
            const int b2 = row >> 8, j = row & 255;
            kvT[(((size_t)b2 * D + tid) * N + j) * 2 + (m - 1)] = f2bf(acc[r]);
        }
    }
}

// ---------------------------------------------------------------------------
// ymap
// ---------------------------------------------------------------------------
__global__ void ymap_kernel(const float* __restrict__ y,
                            const float* __restrict__ we_add, const float* __restrict__ be_add,
                            const float* __restrict__ we_mul, const float* __restrict__ be_mul,
                            const float* __restrict__ wx_add, const float* __restrict__ bx_add,
                            const float* __restrict__ wx_mul, const float* __restrict__ bx_mul,
                            float* __restrict__ ye1, float* __restrict__ ye2,
                            float* __restrict__ yx1, float* __restrict__ yx2) {
    const int b = blockIdx.x >> 2;
    const int m = blockIdx.x & 3;
    const int f = threadIdx.x;
    const float* W; const float* B; float* O;
    switch (m) {
        case 0:  W = we_add; B = be_add; O = ye1; break;
        case 1:  W = we_mul; B = be_mul; O = ye2; break;
        case 2:  W = wx_add; B = bx_add; O = yx1; break;
        default: W = wx_mul; B = bx_mul; O = yx2; break;
    }
    float acc = B[f];
    for (int k = 0; k < YD; ++k)
        acc += y[b * YD + k] * W[k * D + f];
    O[b * D + f] = acc;
}

// ---------------------------------------------------------------------------
// za partial stats
// ---------------------------------------------------------------------------
__global__ void za_part_kernel(const float* __restrict__ a,
                               float* __restrict__ psum, float* __restrict__ psumsq,
                               float* __restrict__ pmin, float* __restrict__ pmax) {
    const int blk  = blockIdx.x;
    const int feat = threadIdx.x;
    const float* base = a + (size_t)blk * 256 * E + feat;
    float s = 0.f, ss = 0.f, mn = INFINITY, mx = -INFINITY;
    for (int r = 0; r < 256; ++r) {
        const float v = base[(size_t)r * E];
        s += v; ss += v * v; mn = fminf(mn, v); mx = fmaxf(mx, v);
    }
    const int o = blk * E + feat;
    psum[o] = s; psumsq[o] = ss; pmin[o] = mn; pmax[o] = mx;
}

__global__ void za_reduce_kernel(const float* __restrict__ psum, const float* __restrict__ psumsq,
                                 const float* __restrict__ pmin, const float* __restrict__ pmax,
                                 float* __restrict__ za) {
    const int b = blockIdx.x;
    const int feat = threadIdx.x;
    float s = 0.f, ss = 0.f, mn = INFINITY, mx = -INFINITY;
    for (int c = 0; c < 256; ++c) {
        const int o = (b * 256 + c) * E + feat;
        s += psum[o]; ss += psumsq[o];
        mn = fminf(mn, pmin[o]); mx = fmaxf(mx, pmax[o]);
    }
    const float M = 65536.f;
    const float mean = s / M;
    const float var  = (ss - s * s / M) / (M - 1.f);
    za[b * 512 + feat]       = mean;
    za[b * 512 + 128 + feat] = mn;
    za[b * 512 + 256 + feat] = mx;
    za[b * 512 + 384 + feat] = sqrtf(fmaxf(var, 0.f));
}

__global__ void zx_kernel(const float* __restrict__ x, float* __restrict__ zx) {
    const int b = blockIdx.x;
    const int f = threadIdx.x;
    float s = 0.f, ss = 0.f, mn = INFINITY, mx = -INFINITY;
    for (int i = 0; i < N; ++i) {
        const float v = x[((size_t)b * N + i) * D + f];
        s += v; ss += v * v; mn = fminf(mn, v); mx = fmaxf(mx, v);
    }
    const float M = 256.f;
    const float mean = s / M;
    const float var  = (ss - s * s / M) / (M - 1.f);
    zx[b * 1024 + f]       = mean;
    zx[b * 1024 + 256 + f] = mn;
    zx[b * 1024 + 512 + f] = mx;
    zx[b * 1024 + 768 + f] = sqrtf(fmaxf(var, 0.f));
}

// ---------------------------------------------------------------------------
// MAIN: block = one (b,i). 8 waves; wave mw owns f-block [mw*32, mw*32+32)
// and ALL 64 j of each pass. In-register phase B on GEMM1 frags.
// LDS: double-buffered h tile only (2x32KB). One barrier per pass.
// ---------------------------------------------------------------------------
__global__ __launch_bounds__(512, 4) void main_kernel(
        const float* __restrict__ a,
        const unsigned short* __restrict__ WaddT, const float* __restrict__ Badd,
        const unsigned short* __restrict__ WmulT, const float* __restrict__ Bmul,
        const unsigned short* __restrict__ W2T,  const float* __restrict__ AoutB,
        const float* __restrict__ Q, const unsigned short* __restrict__ kvT,
        const float* __restrict__ ye1, const float* __restrict__ ye2,
        float* __restrict__ ahat, float* __restrict__ wV) {
    const int bi = blockIdx.x;         // b*256 + i
    const int b  = bi >> 8;
    const int tid  = threadIdx.x;
    const int lane = tid & 63;
    const int mw   = tid >> 6;         // wave id 0..7
    const int l15  = lane & 15;
    const int lk   = lane >> 4;        // 0..3

    __shared__ unsigned short hbuf[2][64 * 256];   // 2 x 32 KB, double-buffered

    const float* arow = a + (size_t)bi * N * E;
    float* ahatp      = ahat + (size_t)bi * N * E;
    const unsigned* kvp32 = (const unsigned*)kvT;

    // online softmax state: 8 features per lane (fi = m_*4 + r)
    float sm_m[8], sm_l[8], sm_a[8];
#pragma unroll
    for (int q = 0; q < 8; ++q) { sm_m[q] = -INFINITY; sm_l[q] = 0.f; sm_a[q] = 0.f; }

    for (int t = 0; t < 4; ++t) {
        const int j0 = t * 64;
        unsigned short* hb = hbuf[t & 1];

        // ---- GEMM1: acc[f][j] for (Wadd,+1-bias) and (Wmul,bias) ----
        f32x4 acc1[2][4], acc2[2][4];
#pragma unroll
        for (int m_ = 0; m_ < 2; ++m_) {
            const int f0 = mw * 32 + m_ * 16 + lk * 4;
            f32x4 b1 = *(const f32x4*)(Badd + f0);
            f32x4 b2 = *(const f32x4*)(Bmul + f0);
            b1.x += 1.f; b1.y += 1.f; b1.z += 1.f; b1.w += 1.f;
#pragma unroll
            for (int n_ = 0; n_ < 4; ++n_) { acc1[m_][n_] = b1; acc2[m_][n_] = b2; }
        }
#pragma unroll
        for (int ks = 0; ks < 4; ++ks) {
            short8 bfrg[4];
#pragma unroll
            for (int n_ = 0; n_ < 4; ++n_) {
                const int jg = j0 + n_ * 16 + l15;
                const float* ap = arow + (size_t)jg * E + ks * 32 + lk * 8;
                const f32x4 v0 = *(const f32x4*)(ap);
                const f32x4 v1 = *(const f32x4*)(ap + 4);
                u16x8 pk;
                pk.s0 = f2bf(v0.x); pk.s1 = f2bf(v0.y); pk.s2 = f2bf(v0.z); pk.s3 = f2bf(v0.w);
                pk.s4 = f2bf(v1.x); pk.s5 = f2bf(v1.y); pk.s6 = f2bf(v1.z); pk.s7 = f2bf(v1.w);
                bfrg[n_] = *(short8*)&pk;
            }
#pragma unroll
            for (int m_ = 0; m_ < 2; ++m_) {
                const int frow = mw * 32 + m_ * 16 + l15;
                const short8 wa = *(const short8*)(WaddT + frow * 128 + ks * 32 + lk * 8);
                const short8 wm = *(const short8*)(WmulT + frow * 128 + ks * 32 + lk * 8);
#pragma unroll
                for (int n_ = 0; n_ < 4; ++n_) {
                    acc1[m_][n_] = mfma16(wa, bfrg[n_], acc1[m_][n_]);
                    acc2[m_][n_] = mfma16(wm, bfrg[n_], acc2[m_][n_]);
                }
            }
        }

        // ---- phase B (in-register): Y, h->LDS, online softmax over 4 j's ----
#pragma unroll
        for (int m_ = 0; m_ < 2; ++m_) {
            const int f0 = mw * 32 + m_ * 16 + lk * 4;
            f32x4 qv  = *(const f32x4*)(Q + (size_t)bi * D + f0);
            f32x4 e1v = *(const f32x4*)(ye1 + b * D + f0);
            f32x4 e2v = *(const f32x4*)(ye2 + b * D + f0);
            qv.x *= RSQRT_F; qv.y *= RSQRT_F; qv.z *= RSQRT_F; qv.w *= RSQRT_F;
            e2v.x += 1.f; e2v.y += 1.f; e2v.z += 1.f; e2v.w += 1.f;
            u16x4 hp[4];
#pragma unroll
            for (int r = 0; r < 4; ++r) {
                const size_t kbase = (size_t)(b * D + f0 + r) * N + j0 + l15;
                float yv[4], vv[4];
#pragma unroll
                for (int n_ = 0; n_ < 4; ++n_) {
                    const unsigned pk = kvp32[kbase + n_ * 16];
                    const float kf = bf2f((unsigned short)(pk & 0xffffu));
                    vv[n_] = bf2f((unsigned short)(pk >> 16));
                    const float qk = qv[r] * kf;
                    yv[n_] = qk * acc1[m_][n_][r] + acc2[m_][n_][r];
                    hp[n_][r] = f2bf(e1v[r] + e2v[r] * yv[n_]);
                }
                const int fi = m_ * 4 + r;
                const float tm = fmaxf(fmaxf(yv[0], yv[1]), fmaxf(yv[2], yv[3]));
                const float M  = fmaxf(sm_m[fi], tm);
                const float sc = __expf(sm_m[fi] - M);
                const float e0 = __expf(yv[0] - M);
                const float e1 = __expf(yv[1] - M);
                const float e2 = __expf(yv[2] - M);
                const float e3 = __expf(yv[3] - M);
                sm_l[fi] = sm_l[fi] * sc + e0 + e1 + e2 + e3;
                sm_a[fi] = sm_a[fi] * sc + e0 * vv[0] + e1 * vv[1] + e2 * vv[2] + e3 * vv[3];
                sm_m[fi] = M;
            }
#pragma unroll
            for (int n_ = 0; n_ < 4; ++n_) {
                const int jl = n_ * 16 + l15;
                const unsigned addr = (unsigned)(jl * 512 + f0 * 2) ^ ((jl & 7) << 4);
                *(u16x4*)((char*)hb + addr) = hp[n_];
            }
        }
        __syncthreads();   // h tile ready (also fences prior pass per barrier chain)

        // ---- GEMM2: ahat^T[e][j] = W2T @ h^T ----
        f32x4 accO[4];
#pragma unroll
        for (int n2 = 0; n2 < 4; ++n2) accO[n2] = (f32x4){0.f, 0.f, 0.f, 0.f};
#pragma unroll
        for (int ks = 0; ks < 8; ++ks) {
            const int foff = ks * 32 + lk * 8;
            const int erow = mw * 16 + l15;
            const short8 w2 = *(const short8*)(W2T + erow * 256 + foff);
#pragma unroll
            for (int n2 = 0; n2 < 4; ++n2) {
                const int jl = n2 * 16 + l15;
                const unsigned addr = (unsigned)(jl * 512 + foff * 2) ^ ((jl & 7) << 4);
                const short8 hbf = *(const short8*)((const char*)hb + addr);
                accO[n2] = mfma16(w2, hbf, accO[n2]);
            }
        }
        {
            const int eb = mw * 16 + lk * 4;
            const f32x4 bias2 = *(const f32x4*)(AoutB + eb);
#pragma unroll
            for (int n2 = 0; n2 < 4; ++n2) {
                const int jg = j0 + n2 * 16 + l15;
                f32x4 ov = accO[n2] + bias2;
                *(f32x4*)(ahatp + (size_t)jg * E + eb) = ov;
            }
        }
        // no barrier here: next pass writes the OTHER h buffer; the next
        // pass's barrier guarantees this GEMM2 is done before reuse.
    }

    // ---- reduce softmax state across l15 (16 j-columns) via butterfly ----
#pragma unroll
    for (int st = 1; st <= 8; st <<= 1) {
#pragma unroll
        for (int fi = 0; fi < 8; ++fi) {
            const float om = __shfl_xor(sm_m[fi], st, 64);
            const float ol = __shfl_xor(sm_l[fi], st, 64);
            const float oa = __shfl_xor(sm_a[fi], st, 64);
            const float M  = fmaxf(sm_m[fi], om);
            const float s1 = __expf(sm_m[fi] - M);
            const float s2 = __expf(om - M);
            sm_l[fi] = sm_l[fi] * s1 + ol * s2;
            sm_a[fi] = sm_a[fi] * s1 + oa * s2;
            sm_m[fi] = M;
        }
    }
    if (l15 == 0) {
#pragma unroll
        for (int m_ = 0; m_ < 2; ++m_)
#pragma unroll
            for (int r = 0; r < 4; ++r) {
                const int fi = m_ * 4 + r;
                const int f  = mw * 32 + m_ * 16 + lk * 4 + r;
                wV[(size_t)bi * D + f] = sm_a[fi] / sm_l[fi];
            }
    }
}

// ---------------------------------------------------------------------------
// xhat = (yx1 + (yx2+1)*wV) @ x_out_w + x_out_b
// ---------------------------------------------------------------------------
__global__ void xhat_kernel(const float* __restrict__ wV,
                            const float* __restrict__ yx1, const float* __restrict__ yx2,
                            const float* __restrict__ W, const float* __restrict__ B,
                            float* __restrict__ out) {
    const int rg = blockIdx.x;
    const int tid = threadIdx.x;
    __shared__ float xr[8][D];
#pragma unroll
    for (int r = 0; r < 8; ++r) {
        const int row = rg * 8 + r;
        const int b = row >> 8;
        xr[r][tid] = yx1[b * D + tid] + (yx2[b * D + tid] + 1.f) * wV[(size_t)row * D + tid];
    }
    __syncthreads();
    float acc[8];
    const float bb = B[tid];
#pragma unroll
    for (int r = 0; r < 8; ++r) acc[r] = bb;
    for (int k = 0; k < D; ++k) {
        const float w = W[k * D + tid];
#pragma unroll
        for (int r = 0; r < 8; ++r) acc[r] += xr[r][k] * w;
    }
#pragma unroll
    for (int r = 0; r < 8; ++r)
        out[(size_t)(rg * 8 + r) * D + tid] = acc[r];
}

// ---------------------------------------------------------------------------
// yhat MLP
// ---------------------------------------------------------------------------
__global__ void yhat_kernel(const float* __restrict__ y,
                            const float* __restrict__ za, const float* __restrict__ zx,
                            const float* __restrict__ yyw, const float* __restrict__ yyb,
                            const float* __restrict__ xyw, const float* __restrict__ xyb,
                            const float* __restrict__ ayw, const float* __restrict__ ayb,
                            const float* __restrict__ w1, const float* __restrict__ b1,
                            const float* __restrict__ w2, const float* __restrict__ b2,
                            float* __restrict__ out) {
    const int b = blockIdx.x;
    const int o = threadIdx.x;
    __shared__ float h1[YD], h2[YD];
    float acc = yyb[o] + xyb[o] + ayb[o];
    for (int k = 0; k < YD; ++k)   acc += y[b * YD + k]    * yyw[k * YD + o];
    for (int k = 0; k < 512; ++k)  acc += za[b * 512 + k]  * ayw[k * YD + o];
    for (int k = 0; k < 1024; ++k) acc += zx[b * 1024 + k] * xyw[k * YD + o];
    h1[o] = acc;
    __syncthreads();
    float acc2 = b1[o];
    for (int k = 0; k < YD; ++k) acc2 += h1[k] * w1[k * YD + o];
    h2[o] = fmaxf(acc2, 0.f);
    __syncthreads();
    float acc3 = b2[o];
    for (int k = 0; k < YD; ++k) acc3 += h2[k] * w2[k * YD + o];
    out[b * YD + o] = acc3;
}

// ---------------------------------------------------------------------------
extern "C" void kernel_launch(void* const* d_in, const int* in_sizes, int n_in,
                              void* d_out, int out_size, void* d_ws, size_t ws_size,
                              hipStream_t stream) {
    const float* x         = (const float*)d_in[0];
    const float* a         = (const float*)d_in[1];
    const float* y         = (const float*)d_in[2];
    const float* qw        = (const float*)d_in[3];  const float* qb        = (const float*)d_in[4];
    const float* kw        = (const float*)d_in[5];  const float* kb        = (const float*)d_in[6];
    const float* vw        = (const float*)d_in[7];  const float* vb        = (const float*)d_in[8];
    const float* a2x_add_w = (const float*)d_in[9];  const float* a2x_add_b = (const float*)d_in[10];
    const float* a2x_mul_w = (const float*)d_in[11]; const float* a2x_mul_b = (const float*)d_in[12];
    const float* y2e_mul_w = (const float*)d_in[13]; const float* y2e_mul_b = (const float*)d_in[14];
    const float* y2e_add_w = (const float*)d_in[15]; const float* y2e_add_b = (const float*)d_in[16];
    const float* y2x_mul_w = (const float*)d_in[17]; const float* y2x_mul_b = (const float*)d_in[18];
    const float* y2x_add_w = (const float*)d_in[19]; const float* y2x_add_b = (const float*)d_in[20];
    const float* y_y_w     = (const float*)d_in[21]; const float* y_y_b     = (const float*)d_in[22];
    const float* x_y_w     = (const float*)d_in[23]; const float* x_y_b     = (const float*)d_in[24];
    const float* a_y_w     = (const float*)d_in[25]; const float* a_y_b     = (const float*)d_in[26];
    const float* x_out_w   = (const float*)d_in[27]; const float* x_out_b   = (const float*)d_in[28];
    const float* a_out_w   = (const float*)d_in[29]; const float* a_out_b   = (const float*)d_in[30];
    const float* y_out1_w  = (const float*)d_in[31]; const float* y_out1_b  = (const float*)d_in[32];
    const float* y_out2_w  = (const float*)d_in[33]; const float* y_out2_b  = (const float*)d_in[34];

    float* ws = (float*)d_ws;
    float* Q      = ws;                                   // 131072
    unsigned short* kvT = (unsigned short*)(ws + 131072); // 262144 u16 = 131072 f
    float* wV     = ws + 262144;                          // 131072
    float* ye1    = ws + 393216;   // 512
    float* ye2    = ws + 393728;
    float* yx1    = ws + 394240;
    float* yx2    = ws + 394752;
    float* psum   = ws + 395264;   // 65536
    float* psumsq = ws + 460800;
    float* pminb  = ws + 526336;
    float* pmaxb  = ws + 591872;
    float* za     = ws + 657408;   // 1024
    float* zx     = ws + 658432;   // 2048
    unsigned short* WaddT = (unsigned short*)(ws + 660480);  // 32768 u16
    unsigned short* WmulT = (unsigned short*)(ws + 676864);
    unsigned short* W2T   = (unsigned short*)(ws + 693248);

    float* xhat = (float*)d_out;
    float* ahat = (float*)d_out + 131072;
    float* yhat = (float*)d_out + 16908288;

    wt_kernel<<<384, 256, 0, stream>>>(a2x_add_w, a2x_mul_w, a_out_w, WaddT, WmulT, W2T);
    qkv_kernel<<<192, 256, 0, stream>>>(x, qw, qb, kw, kb, vw, vb, Q, kvT);
    ymap_kernel<<<8, 256, 0, stream>>>(y, y2e_add_w, y2e_add_b, y2e_mul_w, y2e_mul_b,
                                       y2x_add_w, y2x_add_b, y2x_mul_w, y2x_mul_b,
                                       ye1, ye2, yx1, yx2);
    za_part_kernel<<<512, 128, 0, stream>>>(a, psum, psumsq, pminb, pmaxb);
    zx_kernel<<<2, 256, 0, stream>>>(x, zx);
    main_kernel<<<512, 512, 0, stream>>>(a, WaddT, a2x_add_b, WmulT, a2x_mul_b,
                                         W2T, a_out_b, Q, kvT, ye1, ye2, ahat, wV);
    xhat_kernel<<<64, 256, 0, stream>>>(wV, yx1, yx2, x_out_w, x_out_b, xhat);
    za_reduce_kernel<<<2, 128, 0, stream>>>(psum, psumsq, pminb, pmaxb, za);
    yhat_kernel<<<2, 128, 0, stream>>>(y, za, zx, y_y_w, y_y_b, x_y_w, x_y_b, a_y_w, a_y_b,
                                       y_out1_w, y_out1_b, y_out2_w, y_out2_b, yhat);
}

// Round 4
// 398.317 us; speedup vs baseline: 1.6561x; 1.6561x over previous
//
#include <hip/hip_runtime.h>
#include <hip/hip_bf16.h>
#include <cstddef>

// Problem constants
constexpr int BS = 2;
constexpr int N  = 256;
constexpr int D  = 256;   // NH_N
constexpr int E  = 128;   // NH_E
constexpr int YD = 128;   // NH_Y
constexpr float RSQRT_F = 0.17677669529663687f;  // 1/sqrt(32)

typedef __attribute__((ext_vector_type(8))) short     short8;
typedef __attribute__((ext_vector_type(4))) float     f32x4;
typedef __attribute__((ext_vector_type(4))) unsigned short u16x4;
typedef __attribute__((ext_vector_type(8))) unsigned short u16x8;

__device__ __forceinline__ unsigned short f2bf(float x) {
    unsigned u = __float_as_uint(x);
    unsigned r = (u + 0x7fffu + ((u >> 16) & 1u)) >> 16;   // RNE
    return (unsigned short)r;
}
__device__ __forceinline__ float bf2f(unsigned short h) {
    return __uint_as_float(((unsigned)h) << 16);
}
__device__ __forceinline__ f32x4 mfma16(short8 a, short8 b, f32x4 c) {
    return __builtin_amdgcn_mfma_f32_16x16x32_bf16(a, b, c, 0, 0, 0);
}

// ---------------------------------------------------------------------------
// prep: transpose + bf16-convert the three big weight matrices
// ---------------------------------------------------------------------------
__global__ void wt_kernel(const float* __restrict__ Wadd, const float* __restrict__ Wmul,
                          const float* __restrict__ W2,
                          unsigned short* __restrict__ WaddT, unsigned short* __restrict__ WmulT,
                          unsigned short* __restrict__ W2T) {
    int idx = blockIdx.x * 256 + threadIdx.x;
    int s = idx >> 15;          // 32768 per section
    int k = idx & 32767;
    if (s == 0)      { int f = k >> 7, e = k & 127; WaddT[k] = f2bf(Wadd[e * 256 + f]); }
    else if (s == 1) { int f = k >> 7, e = k & 127; WmulT[k] = f2bf(Wmul[e * 256 + f]); }
    else             { int f = k & 255, e = k >> 8; W2T[k]   = f2bf(W2[f * 128 + e]); }
}

// ---------------------------------------------------------------------------
// K1: Q = x@qw+qb (fp32, row-major); K/V -> kvT bf16 transposed interleaved:
// kvT u16 layout: (( b*256 + f )*256 + j)*2 + {0:K,1:V}
// ---------------------------------------------------------------------------
__global__ void qkv_kernel(const float* __restrict__ x,
                           const float* __restrict__ qw, const float* __restrict__ qb,
                           const float* __restrict__ kw, const float* __restrict__ kb,
                           const float* __restrict__ vw, const float* __restrict__ vb,
                           float* __restrict__ Q, unsigned short* __restrict__ kvT) {
    const int m  = blockIdx.x >> 6;
    const int rg = blockIdx.x & 63;
    const float* W = (m == 0) ? qw : (m == 1) ? kw : vw;
    const float* B = (m == 0) ? qb : (m == 1) ? kb : vb;

    __shared__ float xs[8][D];
    const int tid = threadIdx.x;
#pragma unroll
    for (int r = 0; r < 8; ++r)
        xs[r][tid] = x[(size_t)(rg * 8 + r) * D + tid];
    __syncthreads();

    float acc[8];
    const float bb = B[tid];
#pragma unroll
    for (int r = 0; r < 8; ++r) acc[r] = bb;
    for (int k = 0; k < D; ++k) {
        const float w = W[k * D + tid];
#pragma unroll
        for (int r = 0; r < 8; ++r) acc[r] += xs[r][k] * w;
    }
#pragma unroll
    for (int r = 0; r < 8; ++r) {
        const int row = rg * 8 + r;
        if (m == 0) Q[(size_t)row * D + tid] = acc[r];
        else {
            const int b2 = row >> 8, j = row & 255;
            kvT[(((size_t)b2 * D + tid) * N + j) * 2 + (m - 1)] = f2bf(acc[r]);
        }
    }
}

// ---------------------------------------------------------------------------
// ymap
// ---------------------------------------------------------------------------
__global__ void ymap_kernel(const float* __restrict__ y,
                            const float* __restrict__ we_add, const float* __restrict__ be_add,
                            const float* __restrict__ we_mul, const float* __restrict__ be_mul,
                            const float* __restrict__ wx_add, const float* __restrict__ bx_add,
                            const float* __restrict__ wx_mul, const float* __restrict__ bx_mul,
                            float* __restrict__ ye1, float* __restrict__ ye2,
                            float* __restrict__ yx1, float* __restrict__ yx2) {
    const int b = blockIdx.x >> 2;
    const int m = blockIdx.x & 3;
    const int f = threadIdx.x;
    const float* W; const float* B; float* O;
    switch (m) {
        case 0:  W = we_add; B = be_add; O = ye1; break;
        case 1:  W = we_mul; B = be_mul; O = ye2; break;
        case 2:  W = wx_add; B = bx_add; O = yx1; break;
        default: W = wx_mul; B = bx_mul; O = yx2; break;
    }
    float acc = B[f];
    for (int k = 0; k < YD; ++k)
        acc += y[b * YD + k] * W[k * D + f];
    O[b * D + f] = acc;
}

// ---------------------------------------------------------------------------
// za partial stats
// ---------------------------------------------------------------------------
__global__ void za_part_kernel(const float* __restrict__ a,
                               float* __restrict__ psum, float* __restrict__ psumsq,
                               float* __restrict__ pmin, float* __restrict__ pmax) {
    const int blk  = blockIdx.x;
    const int feat = threadIdx.x;
    const float* base = a + (size_t)blk * 256 * E + feat;
    float s = 0.f, ss = 0.f, mn = INFINITY, mx = -INFINITY;
    for (int r = 0; r < 256; ++r) {
        const float v = base[(size_t)r * E];
        s += v; ss += v * v; mn = fminf(mn, v); mx = fmaxf(mx, v);
    }
    const int o = blk * E + feat;
    psum[o] = s; psumsq[o] = ss; pmin[o] = mn; pmax[o] = mx;
}

// grid 2, block 512: 4-way k-split + LDS reduce
__global__ void za_reduce_kernel(const float* __restrict__ psum, const float* __restrict__ psumsq,
                                 const float* __restrict__ pmin, const float* __restrict__ pmax,
                                 float* __restrict__ za) {
    const int b = blockIdx.x;
    const int feat = threadIdx.x & 127;
    const int g = threadIdx.x >> 7;
    float s = 0.f, ss = 0.f, mn = INFINITY, mx = -INFINITY;
    for (int c = g * 64; c < g * 64 + 64; ++c) {
        const int o = (b * 256 + c) * E + feat;
        s += psum[o]; ss += psumsq[o];
        mn = fminf(mn, pmin[o]); mx = fmaxf(mx, pmax[o]);
    }
    __shared__ float rs[4][128], rss[4][128], rmn[4][128], rmx[4][128];
    rs[g][feat] = s; rss[g][feat] = ss; rmn[g][feat] = mn; rmx[g][feat] = mx;
    __syncthreads();
    if (g == 0) {
#pragma unroll
        for (int gg = 1; gg < 4; ++gg) {
            s += rs[gg][feat]; ss += rss[gg][feat];
            mn = fminf(mn, rmn[gg][feat]); mx = fmaxf(mx, rmx[gg][feat]);
        }
        const float M = 65536.f;
        const float mean = s / M;
        const float var  = (ss - s * s / M) / (M - 1.f);
        za[b * 512 + feat]       = mean;
        za[b * 512 + 128 + feat] = mn;
        za[b * 512 + 256 + feat] = mx;
        za[b * 512 + 384 + feat] = sqrtf(fmaxf(var, 0.f));
    }
}

__global__ void zx_kernel(const float* __restrict__ x, float* __restrict__ zx) {
    const int b = blockIdx.x;
    const int f = threadIdx.x;
    float s = 0.f, ss = 0.f, mn = INFINITY, mx = -INFINITY;
    for (int i = 0; i < N; ++i) {
        const float v = x[((size_t)b * N + i) * D + f];
        s += v; ss += v * v; mn = fminf(mn, v); mx = fmaxf(mx, v);
    }
    const float M = 256.f;
    const float mean = s / M;
    const float var  = (ss - s * s / M) / (M - 1.f);
    zx[b * 1024 + f]       = mean;
    zx[b * 1024 + 256 + f] = mn;
    zx[b * 1024 + 512 + f] = mx;
    zx[b * 1024 + 768 + f] = sqrtf(fmaxf(var, 0.f));
}

// ---------------------------------------------------------------------------
// MAIN: block = one (b,i). 8 waves; wave w owns f-block [w*32, w*32+32).
// 8 passes x 32 j. a staged to LDS (HBM read once), j processed in two
// 16-wide halves so GEMM1 live accumulators = 4 frags. One barrier/pass.
// ---------------------------------------------------------------------------
__global__ __launch_bounds__(512, 4) void main_kernel(
        const float* __restrict__ a,
        const unsigned short* __restrict__ WaddT, const float* __restrict__ Badd,
        const unsigned short* __restrict__ WmulT, const float* __restrict__ Bmul,
        const unsigned short* __restrict__ W2T,  const float* __restrict__ AoutB,
        const float* __restrict__ Q, const unsigned short* __restrict__ kvT,
        const float* __restrict__ ye1, const float* __restrict__ ye2,
        float* __restrict__ ahat, float* __restrict__ wV) {
    const int bi = blockIdx.x;         // b*256 + i
    const int b  = bi >> 8;
    const int tid  = threadIdx.x;
    const int lane = tid & 63;
    const int w    = tid >> 6;         // wave id 0..7
    const int l15  = lane & 15;
    const int lk   = lane >> 4;        // 0..3

    __shared__ unsigned short abuf[2][32 * 128];   // 2 x 8 KB  a-tile bf16 (swizzled)
    __shared__ unsigned short hbuf[2][32 * 256];   // 2 x 16 KB h bf16 (swizzled)

    const float* arow = a + (size_t)bi * (N * E);
    float* ahatp      = ahat + (size_t)bi * (N * E);
    const unsigned* kvp = (const unsigned*)kvT + (size_t)b * D * N;

    // hoisted per-f constants: f = w*32 + m_*16 + lk*4 + r  (fi = m_*4+r)
    float qs[8], e1c[8], e2c[8], b1c[8], b2c[8];
#pragma unroll
    for (int m_ = 0; m_ < 2; ++m_) {
        const int f0 = w * 32 + m_ * 16 + lk * 4;
        const f32x4 qv = *(const f32x4*)(Q + (size_t)bi * D + f0);
        const f32x4 a1 = *(const f32x4*)(ye1 + b * D + f0);
        const f32x4 a2 = *(const f32x4*)(ye2 + b * D + f0);
        const f32x4 bb1 = *(const f32x4*)(Badd + f0);
        const f32x4 bb2 = *(const f32x4*)(Bmul + f0);
#pragma unroll
        for (int r = 0; r < 4; ++r) {
            const int fi = m_ * 4 + r;
            qs[fi]  = qv[r] * RSQRT_F;
            e1c[fi] = a1[r];
            e2c[fi] = a2[r] + 1.f;
            b1c[fi] = bb1[r] + 1.f;   // (a1 + 1) bias
            b2c[fi] = bb2[r];
        }
    }
    const f32x4 bias2 = *(const f32x4*)(AoutB + w * 16 + lk * 4);

    // online softmax state (no max tracking: |Y| <~ 2.5 by construction)
    float sm_l[8], sm_a[8];
#pragma unroll
    for (int q = 0; q < 8; ++q) { sm_l[q] = 0.f; sm_a[q] = 0.f; }

    const int sjl = tid >> 4;          // staging row 0..31
    const int seq = tid & 15;          // staging 8-float chunk
    const unsigned saddr = ((unsigned)(sjl * 256 + seq * 16)) ^ ((unsigned)(sjl & 7) << 4);

    // prologue: stage pass 0
    {
        const float* ap = arow + (size_t)sjl * E + seq * 8;
        const f32x4 v0 = *(const f32x4*)ap;
        const f32x4 v1 = *(const f32x4*)(ap + 4);
        u16x8 pk;
        pk.s0 = f2bf(v0.x); pk.s1 = f2bf(v0.y); pk.s2 = f2bf(v0.z); pk.s3 = f2bf(v0.w);
        pk.s4 = f2bf(v1.x); pk.s5 = f2bf(v1.y); pk.s6 = f2bf(v1.z); pk.s7 = f2bf(v1.w);
        *(u16x8*)((char*)abuf[0] + saddr) = pk;
    }
    __syncthreads();

    for (int t = 0; t < 8; ++t) {
        const int j0 = t * 32;
        const unsigned short* ab = abuf[t & 1];
        unsigned short* hw = hbuf[t & 1];

        // prefetch next a-tile into registers (latency hides under G1+phaseB)
        f32x4 p0, p1;
        if (t < 7) {
            const float* ap = arow + (size_t)(j0 + 32 + sjl) * E + seq * 8;
            p0 = *(const f32x4*)ap;
            p1 = *(const f32x4*)(ap + 4);
        }

#pragma unroll
        for (int n_ = 0; n_ < 2; ++n_) {
            const int jrow = n_ * 16 + l15;     // 0..31 within pass
            // ---- GEMM1 (16-j half): acc = W^T . a^T ----
            f32x4 acc1[2], acc2[2];
#pragma unroll
            for (int m_ = 0; m_ < 2; ++m_) {
                acc1[m_] = (f32x4){b1c[m_ * 4 + 0], b1c[m_ * 4 + 1], b1c[m_ * 4 + 2], b1c[m_ * 4 + 3]};
                acc2[m_] = (f32x4){b2c[m_ * 4 + 0], b2c[m_ * 4 + 1], b2c[m_ * 4 + 2], b2c[m_ * 4 + 3]};
            }
#pragma unroll
            for (int ks = 0; ks < 4; ++ks) {
                const unsigned baddr = ((unsigned)(jrow * 256 + (ks * 32 + lk * 8) * 2))
                                       ^ ((unsigned)(jrow & 7) << 4);
                const short8 bf = *(const short8*)((const char*)ab + baddr);
#pragma unroll
                for (int m_ = 0; m_ < 2; ++m_) {
                    const int frow = w * 32 + m_ * 16 + l15;
                    const short8 wa = *(const short8*)(WaddT + frow * 128 + ks * 32 + lk * 8);
                    const short8 wm = *(const short8*)(WmulT + frow * 128 + ks * 32 + lk * 8);
                    acc1[m_] = mfma16(wa, bf, acc1[m_]);
                    acc2[m_] = mfma16(wm, bf, acc2[m_]);
                }
            }
            // ---- phase B (in-register): Y, h->LDS, softmax accumulation ----
            const int jg = j0 + jrow;
#pragma unroll
            for (int m_ = 0; m_ < 2; ++m_) {
                u16x4 hp;
#pragma unroll
                for (int r = 0; r < 4; ++r) {
                    const int fi = m_ * 4 + r;
                    const int f  = w * 32 + m_ * 16 + lk * 4 + r;
                    const unsigned pk = kvp[(size_t)f * N + jg];
                    const float kf = bf2f((unsigned short)(pk & 0xffffu));
                    const float vf = bf2f((unsigned short)(pk >> 16));
                    const float yv = qs[fi] * kf * acc1[m_][r] + acc2[m_][r];
                    hp[r] = f2bf(e1c[fi] + e2c[fi] * yv);
                    const float ev = __expf(yv);
                    sm_l[fi] += ev;
                    sm_a[fi] += ev * vf;
                }
                const unsigned haddr = ((unsigned)(jrow * 512 + (w * 32 + m_ * 16 + lk * 4) * 2))
                                       ^ ((unsigned)(jrow & 7) << 4);
                *(u16x4*)((char*)hw + haddr) = hp;
            }
        }

        // ---- write prefetched a-tile to the other buffer ----
        if (t < 7) {
            u16x8 pk;
            pk.s0 = f2bf(p0.x); pk.s1 = f2bf(p0.y); pk.s2 = f2bf(p0.z); pk.s3 = f2bf(p0.w);
            pk.s4 = f2bf(p1.x); pk.s5 = f2bf(p1.y); pk.s6 = f2bf(p1.z); pk.s7 = f2bf(p1.w);
            *(u16x8*)((char*)abuf[(t + 1) & 1] + saddr) = pk;
        }
        __syncthreads();   // h ready; next a-tile ready; abuf[t&1] reads done

        // ---- GEMM2: ahat^T[e][j] = W2T . h^T  (+bias) ----
        f32x4 accO[2];
        accO[0] = bias2; accO[1] = bias2;
#pragma unroll
        for (int ks = 0; ks < 8; ++ks) {
            const int foff = ks * 32 + lk * 8;
            const short8 w2 = *(const short8*)(W2T + (w * 16 + l15) * 256 + foff);
#pragma unroll
            for (int n2 = 0; n2 < 2; ++n2) {
                const int jrow = n2 * 16 + l15;
                const unsigned haddr = ((unsigned)(jrow * 512 + foff * 2))
                                       ^ ((unsigned)(jrow & 7) << 4);
                const short8 hf = *(const short8*)((const char*)hw + haddr);
                accO[n2] = mfma16(w2, hf, accO[n2]);
            }
        }
        {
            const int eb = w * 16 + lk * 4;
#pragma unroll
            for (int n2 = 0; n2 < 2; ++n2) {
                const int jg2 = j0 + n2 * 16 + l15;
                *(f32x4*)(ahatp + (size_t)jg2 * E + eb) = accO[n2];
            }
        }
    }

    // ---- merge softmax partials across l15 (sum over j-columns) ----
#pragma unroll
    for (int st = 1; st <= 8; st <<= 1) {
#pragma unroll
        for (int fi = 0; fi < 8; ++fi) {
            sm_l[fi] += __shfl_xor(sm_l[fi], st, 64);
            sm_a[fi] += __shfl_xor(sm_a[fi], st, 64);
        }
    }
    if (l15 == 0) {
#pragma unroll
        for (int m_ = 0; m_ < 2; ++m_)
#pragma unroll
            for (int r = 0; r < 4; ++r) {
                const int fi = m_ * 4 + r;
                const int f  = w * 32 + m_ * 16 + lk * 4 + r;
                wV[(size_t)bi * D + f] = sm_a[fi] / sm_l[fi];
            }
    }
}

// ---------------------------------------------------------------------------
// xhat = (yx1 + (yx2+1)*wV) @ x_out_w + x_out_b
// ---------------------------------------------------------------------------
__global__ void xhat_kernel(const float* __restrict__ wV,
                            const float* __restrict__ yx1, const float* __restrict__ yx2,
                            const float* __restrict__ W, const float* __restrict__ B,
                            float* __restrict__ out) {
    const int rg = blockIdx.x;
    const int tid = threadIdx.x;
    __shared__ float xr[8][D];
#pragma unroll
    for (int r = 0; r < 8; ++r) {
        const int row = rg * 8 + r;
        const int b = row >> 8;
        xr[r][tid] = yx1[b * D + tid] + (yx2[b * D + tid] + 1.f) * wV[(size_t)row * D + tid];
    }
    __syncthreads();
    float acc[8];
    const float bb = B[tid];
#pragma unroll
    for (int r = 0; r < 8; ++r) acc[r] = bb;
    for (int k = 0; k < D; ++k) {
        const float w = W[k * D + tid];
#pragma unroll
        for (int r = 0; r < 8; ++r) acc[r] += xr[r][k] * w;
    }
#pragma unroll
    for (int r = 0; r < 8; ++r)
        out[(size_t)(rg * 8 + r) * D + tid] = acc[r];
}

// ---------------------------------------------------------------------------
// yhat MLP — 512 threads, 4-way k-split + LDS reduce
// ---------------------------------------------------------------------------
__global__ void yhat_kernel(const float* __restrict__ y,
                            const float* __restrict__ za, const float* __restrict__ zx,
                            const float* __restrict__ yyw, const float* __restrict__ yyb,
                            const float* __restrict__ xyw, const float* __restrict__ xyb,
                            const float* __restrict__ ayw, const float* __restrict__ ayb,
                            const float* __restrict__ w1, const float* __restrict__ b1,
                            const float* __restrict__ w2, const float* __restrict__ b2,
                            float* __restrict__ out) {
    const int b = blockIdx.x;
    const int tid = threadIdx.x;
    const int o = tid & 127;
    const int q = tid >> 7;
    __shared__ float zy[1664];           // [y(128) | za(512) | zx(1024)]
    for (int idx = tid; idx < 1664; idx += 512) {
        float v;
        if (idx < 128)      v = y[b * YD + idx];
        else if (idx < 640) v = za[b * 512 + idx - 128];
        else                v = zx[b * 1024 + idx - 640];
        zy[idx] = v;
    }
    __syncthreads();
    float p = 0.f;
    if (q == 0) {
        for (int k = 0; k < 128; ++k) p += zy[k] * yyw[k * YD + o];
        for (int k = 0; k < 128; ++k) p += zy[128 + k] * ayw[k * YD + o];
    } else if (q == 1) {
        for (int k = 128; k < 512; ++k) p += zy[128 + k] * ayw[k * YD + o];
    } else if (q == 2) {
        for (int k = 0; k < 512; ++k) p += zy[640 + k] * xyw[k * YD + o];
    } else {
        for (int k = 512; k < 1024; ++k) p += zy[640 + k] * xyw[k * YD + o];
    }
    __shared__ float red[4][128];
    __shared__ float h1s[128], h2s[128];
    red[q][o] = p;
    __syncthreads();
    if (tid < 128) {
        h1s[o] = yyb[o] + xyb[o] + ayb[o] + red[0][o] + red[1][o] + red[2][o] + red[3][o];
    }
    __syncthreads();
    float p2 = 0.f;
    for (int k = q * 32; k < q * 32 + 32; ++k) p2 += h1s[k] * w1[k * YD + o];
    red[q][o] = p2;
    __syncthreads();
    if (tid < 128) h2s[o] = fmaxf(b1[o] + red[0][o] + red[1][o] + red[2][o] + red[3][o], 0.f);
    __syncthreads();
    float p3 = 0.f;
    for (int k = q * 32; k < q * 32 + 32; ++k) p3 += h2s[k] * w2[k * YD + o];
    red[q][o] = p3;
    __syncthreads();
    if (tid < 128) out[b * YD + o] = b2[o] + red[0][o] + red[1][o] + red[2][o] + red[3][o];
}

// ---------------------------------------------------------------------------
extern "C" void kernel_launch(void* const* d_in, const int* in_sizes, int n_in,
                              void* d_out, int out_size, void* d_ws, size_t ws_size,
                              hipStream_t stream) {
    const float* x         = (const float*)d_in[0];
    const float* a         = (const float*)d_in[1];
    const float* y         = (const float*)d_in[2];
    const float* qw        = (const float*)d_in[3];  const float* qb        = (const float*)d_in[4];
    const float* kw        = (const float*)d_in[5];  const float* kb        = (const float*)d_in[6];
    const float* vw        = (const float*)d_in[7];  const float* vb        = (const float*)d_in[8];
    const float* a2x_add_w = (const float*)d_in[9];  const float* a2x_add_b = (const float*)d_in[10];
    const float* a2x_mul_w = (const float*)d_in[11]; const float* a2x_mul_b = (const float*)d_in[12];
    const float* y2e_mul_w = (const float*)d_in[13]; const float* y2e_mul_b = (const float*)d_in[14];
    const float* y2e_add_w = (const float*)d_in[15]; const float* y2e_add_b = (const float*)d_in[16];
    const float* y2x_mul_w = (const float*)d_in[17]; const float* y2x_mul_b = (const float*)d_in[18];
    const float* y2x_add_w = (const float*)d_in[19]; const float* y2x_add_b = (const float*)d_in[20];
    const float* y_y_w     = (const float*)d_in[21]; const float* y_y_b     = (const float*)d_in[22];
    const float* x_y_w     = (const float*)d_in[23]; const float* x_y_b     = (const float*)d_in[24];
    const float* a_y_w     = (const float*)d_in[25]; const float* a_y_b     = (const float*)d_in[26];
    const float* x_out_w   = (const float*)d_in[27]; const float* x_out_b   = (const float*)d_in[28];
    const float* a_out_w   = (const float*)d_in[29]; const float* a_out_b   = (const float*)d_in[30];
    const float* y_out1_w  = (const float*)d_in[31]; const float* y_out1_b  = (const float*)d_in[32];
    const float* y_out2_w  = (const float*)d_in[33]; const float* y_out2_b  = (const float*)d_in[34];

    float* ws = (float*)d_ws;
    float* Q      = ws;                                   // 131072
    unsigned short* kvT = (unsigned short*)(ws + 131072); // 262144 u16 = 131072 f
    float* wV     = ws + 262144;                          // 131072
    float* ye1    = ws + 393216;   // 512
    float* ye2    = ws + 393728;
    float* yx1    = ws + 394240;
    float* yx2    = ws + 394752;
    float* psum   = ws + 395264;   // 65536
    float* psumsq = ws + 460800;
    float* pminb  = ws + 526336;
    float* pmaxb  = ws + 591872;
    float* za     = ws + 657408;   // 1024
    float* zx     = ws + 658432;   // 2048
    unsigned short* WaddT = (unsigned short*)(ws + 660480);  // 32768 u16
    unsigned short* WmulT = (unsigned short*)(ws + 676864);
    unsigned short* W2T   = (unsigned short*)(ws + 693248);

    float* xhat = (float*)d_out;
    float* ahat = (float*)d_out + 131072;
    float* yhat = (float*)d_out + 16908288;

    wt_kernel<<<384, 256, 0, stream>>>(a2x_add_w, a2x_mul_w, a_out_w, WaddT, WmulT, W2T);
    qkv_kernel<<<192, 256, 0, stream>>>(x, qw, qb, kw, kb, vw, vb, Q, kvT);
    ymap_kernel<<<8, 256, 0, stream>>>(y, y2e_add_w, y2e_add_b, y2e_mul_w, y2e_mul_b,
                                       y2x_add_w, y2x_add_b, y2x_mul_w, y2x_mul_b,
                                       ye1, ye2, yx1, yx2);
    za_part_kernel<<<512, 128, 0, stream>>>(a, psum, psumsq, pminb, pmaxb);
    zx_kernel<<<2, 256, 0, stream>>>(x, zx);
    main_kernel<<<512, 512, 0, stream>>>(a, WaddT, a2x_add_b, WmulT, a2x_mul_b,
                                         W2T, a_out_b, Q, kvT, ye1, ye2, ahat, wV);
    xhat_kernel<<<64, 256, 0, stream>>>(wV, yx1, yx2, x_out_w, x_out_b, xhat);
    za_reduce_kernel<<<2, 512, 0, stream>>>(psum, psumsq, pminb, pmaxb, za);
    yhat_kernel<<<2, 512, 0, stream>>>(y, za, zx, y_y_w, y_y_b, x_y_w, x_y_b, a_y_w, a_y_b,
                                       y_out1_w, y_out1_b, y_out2_w, y_out2_b, yhat);
}

// Round 5
// 181.932 us; speedup vs baseline: 3.6257x; 2.1894x over previous
//
#include <hip/hip_runtime.h>
#include <hip/hip_bf16.h>
#include <cstddef>

// Problem constants
constexpr int BS = 2;
constexpr int N  = 256;
constexpr int D  = 256;   // NH_N
constexpr int E  = 128;   // NH_E
constexpr int YD = 128;   // NH_Y
constexpr float RSQRT_F = 0.17677669529663687f;  // 1/sqrt(32)

typedef __attribute__((ext_vector_type(8))) short     short8;
typedef __attribute__((ext_vector_type(4))) float     f32x4;
typedef __attribute__((ext_vector_type(4))) unsigned short u16x4;
typedef __attribute__((ext_vector_type(8))) unsigned short u16x8;

__device__ __forceinline__ unsigned short f2bf(float x) {
    unsigned u = __float_as_uint(x);
    unsigned r = (u + 0x7fffu + ((u >> 16) & 1u)) >> 16;   // RNE
    return (unsigned short)r;
}
__device__ __forceinline__ float bf2f(unsigned short h) {
    return __uint_as_float(((unsigned)h) << 16);
}
__device__ __forceinline__ f32x4 mfma16(short8 a, short8 b, f32x4 c) {
    return __builtin_amdgcn_mfma_f32_16x16x32_bf16(a, b, c, 0, 0, 0);
}

// ---------------------------------------------------------------------------
// prep: transpose + bf16-convert the three big weight matrices
// ---------------------------------------------------------------------------
__global__ void wt_kernel(const float* __restrict__ Wadd, const float* __restrict__ Wmul,
                          const float* __restrict__ W2,
                          unsigned short* __restrict__ WaddT, unsigned short* __restrict__ WmulT,
                          unsigned short* __restrict__ W2T) {
    int idx = blockIdx.x * 256 + threadIdx.x;
    int s = idx >> 15;          // 32768 per section
    int k = idx & 32767;
    if (s == 0)      { int f = k >> 7, e = k & 127; WaddT[k] = f2bf(Wadd[e * 256 + f]); }
    else if (s == 1) { int f = k >> 7, e = k & 127; WmulT[k] = f2bf(Wmul[e * 256 + f]); }
    else             { int f = k & 255, e = k >> 8; W2T[k]   = f2bf(W2[f * 128 + e]); }
}

// ---------------------------------------------------------------------------
// K1: Q = x@qw+qb (fp32, row-major); K/V -> kvJ bf16 row-major interleaved:
// kvJ u16 layout: ((b*256 + j)*256 + f)*2 + {0:K,1:V}
// ---------------------------------------------------------------------------
__global__ void qkv_kernel(const float* __restrict__ x,
                           const float* __restrict__ qw, const float* __restrict__ qb,
                           const float* __restrict__ kw, const float* __restrict__ kb,
                           const float* __restrict__ vw, const float* __restrict__ vb,
                           float* __restrict__ Q, unsigned short* __restrict__ kvJ) {
    const int m  = blockIdx.x >> 6;
    const int rg = blockIdx.x & 63;
    const float* W = (m == 0) ? qw : (m == 1) ? kw : vw;
    const float* B = (m == 0) ? qb : (m == 1) ? kb : vb;

    __shared__ float xs[8][D];
    const int tid = threadIdx.x;
#pragma unroll
    for (int r = 0; r < 8; ++r)
        xs[r][tid] = x[(size_t)(rg * 8 + r) * D + tid];
    __syncthreads();

    float acc[8];
    const float bb = B[tid];
#pragma unroll
    for (int r = 0; r < 8; ++r) acc[r] = bb;
    for (int k = 0; k < D; ++k) {
        const float w = W[k * D + tid];
#pragma unroll
        for (int r = 0; r < 8; ++r) acc[r] += xs[r][k] * w;
    }
#pragma unroll
    for (int r = 0; r < 8; ++r) {
        const int row = rg * 8 + r;
        if (m == 0) Q[(size_t)row * D + tid] = acc[r];
        else        kvJ[((size_t)row * D + tid) * 2 + (m - 1)] = f2bf(acc[r]);
    }
}

// ---------------------------------------------------------------------------
// ymap
// ---------------------------------------------------------------------------
__global__ void ymap_kernel(const float* __restrict__ y,
                            const float* __restrict__ we_add, const float* __restrict__ be_add,
                            const float* __restrict__ we_mul, const float* __restrict__ be_mul,
                            const float* __restrict__ wx_add, const float* __restrict__ bx_add,
                            const float* __restrict__ wx_mul, const float* __restrict__ bx_mul,
                            float* __restrict__ ye1, float* __restrict__ ye2,
                            float* __restrict__ yx1, float* __restrict__ yx2) {
    const int b = blockIdx.x >> 2;
    const int m = blockIdx.x & 3;
    const int f = threadIdx.x;
    const float* W; const float* B; float* O;
    switch (m) {
        case 0:  W = we_add; B = be_add; O = ye1; break;
        case 1:  W = we_mul; B = be_mul; O = ye2; break;
        case 2:  W = wx_add; B = bx_add; O = yx1; break;
        default: W = wx_mul; B = bx_mul; O = yx2; break;
    }
    float acc = B[f];
    for (int k = 0; k < YD; ++k)
        acc += y[b * YD + k] * W[k * D + f];
    O[b * D + f] = acc;
}

// ---------------------------------------------------------------------------
// za partial stats
// ---------------------------------------------------------------------------
__global__ void za_part_kernel(const float* __restrict__ a,
                               float* __restrict__ psum, float* __restrict__ psumsq,
                               float* __restrict__ pmin, float* __restrict__ pmax) {
    const int blk  = blockIdx.x;
    const int feat = threadIdx.x;
    const float* base = a + (size_t)blk * 256 * E + feat;
    float s = 0.f, ss = 0.f, mn = INFINITY, mx = -INFINITY;
    for (int r = 0; r < 256; ++r) {
        const float v = base[(size_t)r * E];
        s += v; ss += v * v; mn = fminf(mn, v); mx = fmaxf(mx, v);
    }
    const int o = blk * E + feat;
    psum[o] = s; psumsq[o] = ss; pmin[o] = mn; pmax[o] = mx;
}

// grid 2, block 512: 4-way k-split + LDS reduce
__global__ void za_reduce_kernel(const float* __restrict__ psum, const float* __restrict__ psumsq,
                                 const float* __restrict__ pmin, const float* __restrict__ pmax,
                                 float* __restrict__ za) {
    const int b = blockIdx.x;
    const int feat = threadIdx.x & 127;
    const int g = threadIdx.x >> 7;
    float s = 0.f, ss = 0.f, mn = INFINITY, mx = -INFINITY;
    for (int c = g * 64; c < g * 64 + 64; ++c) {
        const int o = (b * 256 + c) * E + feat;
        s += psum[o]; ss += psumsq[o];
        mn = fminf(mn, pmin[o]); mx = fmaxf(mx, pmax[o]);
    }
    __shared__ float rs[4][128], rss[4][128], rmn[4][128], rmx[4][128];
    rs[g][feat] = s; rss[g][feat] = ss; rmn[g][feat] = mn; rmx[g][feat] = mx;
    __syncthreads();
    if (g == 0) {
#pragma unroll
        for (int gg = 1; gg < 4; ++gg) {
            s += rs[gg][feat]; ss += rss[gg][feat];
            mn = fminf(mn, rmn[gg][feat]); mx = fmaxf(mx, rmx[gg][feat]);
        }
        const float M = 65536.f;
        const float mean = s / M;
        const float var  = (ss - s * s / M) / (M - 1.f);
        za[b * 512 + feat]       = mean;
        za[b * 512 + 128 + feat] = mn;
        za[b * 512 + 256 + feat] = mx;
        za[b * 512 + 384 + feat] = sqrtf(fmaxf(var, 0.f));
    }
}

__global__ void zx_kernel(const float* __restrict__ x, float* __restrict__ zx) {
    const int b = blockIdx.x;
    const int f = threadIdx.x;
    float s = 0.f, ss = 0.f, mn = INFINITY, mx = -INFINITY;
    for (int i = 0; i < N; ++i) {
        const float v = x[((size_t)b * N + i) * D + f];
        s += v; ss += v * v; mn = fminf(mn, v); mx = fmaxf(mx, v);
    }
    const float M = 256.f;
    const float mean = s / M;
    const float var  = (ss - s * s / M) / (M - 1.f);
    zx[b * 1024 + f]       = mean;
    zx[b * 1024 + 256 + f] = mn;
    zx[b * 1024 + 512 + f] = mx;
    zx[b * 1024 + 768 + f] = sqrtf(fmaxf(var, 0.f));
}

// ---------------------------------------------------------------------------
// MAIN: block = one (b,i). 8 waves; wave w owns f-block [w*32, w*32+32).
// 8 passes x 32 j, j processed in two 16-wide halves (4 live acc frags).
// a staged to LDS (HBM read once), double-buffered; one barrier per pass.
// __launch_bounds__(512, 2): 2 blocks/CU -> 128-VGPR budget (NO spill).
// ---------------------------------------------------------------------------
__global__ __launch_bounds__(512, 2) void main_kernel(
        const float* __restrict__ a,
        const unsigned short* __restrict__ WaddT, const float* __restrict__ Badd,
        const unsigned short* __restrict__ WmulT, const float* __restrict__ Bmul,
        const unsigned short* __restrict__ W2T,  const float* __restrict__ AoutB,
        const float* __restrict__ Q, const unsigned short* __restrict__ kvJ,
        const float* __restrict__ ye1, const float* __restrict__ ye2,
        float* __restrict__ ahat, float* __restrict__ wV) {
    const int bi = blockIdx.x;         // b*256 + i
    const int b  = bi >> 8;
    const int tid  = threadIdx.x;
    const int lane = tid & 63;
    const int w    = tid >> 6;         // wave id 0..7
    const int l15  = lane & 15;
    const int lk   = lane >> 4;        // 0..3

    __shared__ unsigned short abuf[2][32 * 128];   // 2 x 8 KB  a-tile bf16 (swizzled)
    __shared__ unsigned short hbuf[2][32 * 256];   // 2 x 16 KB h bf16 (swizzled)

    const float* arow = a + (size_t)bi * (N * E);
    float* ahatp      = ahat + (size_t)bi * (N * E);
    const unsigned short* kvb = kvJ + (size_t)b * N * D * 2;

    // hoisted per-f constants: f = w*32 + m_*16 + lk*4 + r  (fi = m_*4+r)
    float qs[8], e1c[8], e2c[8], b1c[8], b2c[8];
#pragma unroll
    for (int m_ = 0; m_ < 2; ++m_) {
        const int f0 = w * 32 + m_ * 16 + lk * 4;
        const f32x4 qv = *(const f32x4*)(Q + (size_t)bi * D + f0);
        const f32x4 a1 = *(const f32x4*)(ye1 + b * D + f0);
        const f32x4 a2 = *(const f32x4*)(ye2 + b * D + f0);
        const f32x4 bb1 = *(const f32x4*)(Badd + f0);
        const f32x4 bb2 = *(const f32x4*)(Bmul + f0);
#pragma unroll
        for (int r = 0; r < 4; ++r) {
            const int fi = m_ * 4 + r;
            qs[fi]  = qv[r] * RSQRT_F;
            e1c[fi] = a1[r];
            e2c[fi] = a2[r] + 1.f;
            b1c[fi] = bb1[r] + 1.f;   // (a1 + 1) bias
            b2c[fi] = bb2[r];
        }
    }
    const f32x4 bias2 = *(const f32x4*)(AoutB + w * 16 + lk * 4);

    // online softmax state (no max tracking: |Y| <~ 2.5 by construction)
    float sm_l[8], sm_a[8];
#pragma unroll
    for (int q = 0; q < 8; ++q) { sm_l[q] = 0.f; sm_a[q] = 0.f; }

    const int sjl = tid >> 4;          // staging row 0..31
    const int seq = tid & 15;          // staging 8-float chunk
    const unsigned saddr = ((unsigned)(sjl * 256 + seq * 16)) ^ ((unsigned)(sjl & 7) << 4);

    // prologue: stage pass 0
    {
        const float* ap = arow + (size_t)sjl * E + seq * 8;
        const f32x4 v0 = *(const f32x4*)ap;
        const f32x4 v1 = *(const f32x4*)(ap + 4);
        u16x8 pk;
        pk.s0 = f2bf(v0.x); pk.s1 = f2bf(v0.y); pk.s2 = f2bf(v0.z); pk.s3 = f2bf(v0.w);
        pk.s4 = f2bf(v1.x); pk.s5 = f2bf(v1.y); pk.s6 = f2bf(v1.z); pk.s7 = f2bf(v1.w);
        *(u16x8*)((char*)abuf[0] + saddr) = pk;
    }
    __syncthreads();

    for (int t = 0; t < 8; ++t) {
        const int j0 = t * 32;
        const unsigned short* ab = abuf[t & 1];
        unsigned short* hw = hbuf[t & 1];

        // prefetch next a-tile into registers (latency hides under G1+phaseB)
        f32x4 p0, p1;
        if (t < 7) {
            const float* ap = arow + (size_t)(j0 + 32 + sjl) * E + seq * 8;
            p0 = *(const f32x4*)ap;
            p1 = *(const f32x4*)(ap + 4);
        }

#pragma unroll
        for (int n_ = 0; n_ < 2; ++n_) {
            const int jrow = n_ * 16 + l15;     // 0..31 within pass
            const int jg = j0 + jrow;
            // prefetch K/V for this (j, f-block): 2 x 16B vector loads
            u16x8 kvv[2];
#pragma unroll
            for (int m_ = 0; m_ < 2; ++m_)
                kvv[m_] = *(const u16x8*)(kvb + ((size_t)jg * D + w * 32 + m_ * 16 + lk * 4) * 2);

            // ---- GEMM1 (16-j half): acc = W^T . a^T ----
            f32x4 acc1[2], acc2[2];
#pragma unroll
            for (int m_ = 0; m_ < 2; ++m_) {
                acc1[m_] = (f32x4){b1c[m_ * 4 + 0], b1c[m_ * 4 + 1], b1c[m_ * 4 + 2], b1c[m_ * 4 + 3]};
                acc2[m_] = (f32x4){b2c[m_ * 4 + 0], b2c[m_ * 4 + 1], b2c[m_ * 4 + 2], b2c[m_ * 4 + 3]};
            }
#pragma unroll
            for (int ks = 0; ks < 4; ++ks) {
                const unsigned baddr = ((unsigned)(jrow * 256 + (ks * 32 + lk * 8) * 2))
                                       ^ ((unsigned)(jrow & 7) << 4);
                const short8 bf = *(const short8*)((const char*)ab + baddr);
#pragma unroll
                for (int m_ = 0; m_ < 2; ++m_) {
                    const int frow = w * 32 + m_ * 16 + l15;
                    const short8 wa = *(const short8*)(WaddT + frow * 128 + ks * 32 + lk * 8);
                    const short8 wm = *(const short8*)(WmulT + frow * 128 + ks * 32 + lk * 8);
                    acc1[m_] = mfma16(wa, bf, acc1[m_]);
                    acc2[m_] = mfma16(wm, bf, acc2[m_]);
                }
            }
            // ---- phase B (in-register): Y, h->LDS, softmax accumulation ----
#pragma unroll
            for (int m_ = 0; m_ < 2; ++m_) {
                u16x4 hp;
#pragma unroll
                for (int r = 0; r < 4; ++r) {
                    const int fi = m_ * 4 + r;
                    const float kf = bf2f(kvv[m_][2 * r]);
                    const float vf = bf2f(kvv[m_][2 * r + 1]);
                    const float yv = qs[fi] * kf * acc1[m_][r] + acc2[m_][r];
                    hp[r] = f2bf(e1c[fi] + e2c[fi] * yv);
                    const float ev = __expf(yv);
                    sm_l[fi] += ev;
                    sm_a[fi] += ev * vf;
                }
                const unsigned haddr = ((unsigned)(jrow * 512 + (w * 32 + m_ * 16 + lk * 4) * 2))
                                       ^ ((unsigned)(jrow & 7) << 4);
                *(u16x4*)((char*)hw + haddr) = hp;
            }
        }

        // ---- write prefetched a-tile to the other buffer ----
        if (t < 7) {
            u16x8 pk;
            pk.s0 = f2bf(p0.x); pk.s1 = f2bf(p0.y); pk.s2 = f2bf(p0.z); pk.s3 = f2bf(p0.w);
            pk.s4 = f2bf(p1.x); pk.s5 = f2bf(p1.y); pk.s6 = f2bf(p1.z); pk.s7 = f2bf(p1.w);
            *(u16x8*)((char*)abuf[(t + 1) & 1] + saddr) = pk;
        }
        __syncthreads();   // h ready; next a-tile ready; abuf[t&1] reads done

        // ---- GEMM2: ahat^T[e][j] = W2T . h^T  (+bias) ----
        f32x4 accO[2];
        accO[0] = bias2; accO[1] = bias2;
#pragma unroll
        for (int ks = 0; ks < 8; ++ks) {
            const int foff = ks * 32 + lk * 8;
            const short8 w2 = *(const short8*)(W2T + (w * 16 + l15) * 256 + foff);
#pragma unroll
            for (int n2 = 0; n2 < 2; ++n2) {
                const int jrow = n2 * 16 + l15;
                const unsigned haddr = ((unsigned)(jrow * 512 + foff * 2))
                                       ^ ((unsigned)(jrow & 7) << 4);
                const short8 hf = *(const short8*)((const char*)hw + haddr);
                accO[n2] = mfma16(w2, hf, accO[n2]);
            }
        }
        {
            const int eb = w * 16 + lk * 4;
#pragma unroll
            for (int n2 = 0; n2 < 2; ++n2) {
                const int jg2 = j0 + n2 * 16 + l15;
                *(f32x4*)(ahatp + (size_t)jg2 * E + eb) = accO[n2];
            }
        }
    }

    // ---- merge softmax partials across l15 (sum over j-columns) ----
#pragma unroll
    for (int st = 1; st <= 8; st <<= 1) {
#pragma unroll
        for (int fi = 0; fi < 8; ++fi) {
            sm_l[fi] += __shfl_xor(sm_l[fi], st, 64);
            sm_a[fi] += __shfl_xor(sm_a[fi], st, 64);
        }
    }
    if (l15 == 0) {
#pragma unroll
        for (int m_ = 0; m_ < 2; ++m_)
#pragma unroll
            for (int r = 0; r < 4; ++r) {
                const int fi = m_ * 4 + r;
                const int f  = w * 32 + m_ * 16 + lk * 4 + r;
                wV[(size_t)bi * D + f] = sm_a[fi] / sm_l[fi];
            }
    }
}

// ---------------------------------------------------------------------------
// xhat = (yx1 + (yx2+1)*wV) @ x_out_w + x_out_b
// ---------------------------------------------------------------------------
__global__ void xhat_kernel(const float* __restrict__ wV,
                            const float* __restrict__ yx1, const float* __restrict__ yx2,
                            const float* __restrict__ W, const float* __restrict__ B,
                            float* __restrict__ out) {
    const int rg = blockIdx.x;
    const int tid = threadIdx.x;
    __shared__ float xr[8][D];
#pragma unroll
    for (int r = 0; r < 8; ++r) {
        const int row = rg * 8 + r;
        const int b = row >> 8;
        xr[r][tid] = yx1[b * D + tid] + (yx2[b * D + tid] + 1.f) * wV[(size_t)row * D + tid];
    }
    __syncthreads();
    float acc[8];
    const float bb = B[tid];
#pragma unroll
    for (int r = 0; r < 8; ++r) acc[r] = bb;
    for (int k = 0; k < D; ++k) {
        const float w = W[k * D + tid];
#pragma unroll
        for (int r = 0; r < 8; ++r) acc[r] += xr[r][k] * w;
    }
#pragma unroll
    for (int r = 0; r < 8; ++r)
        out[(size_t)(rg * 8 + r) * D + tid] = acc[r];
}

// ---------------------------------------------------------------------------
// yhat MLP — 512 threads, 4-way k-split + LDS reduce
// ---------------------------------------------------------------------------
__global__ void yhat_kernel(const float* __restrict__ y,
                            const float* __restrict__ za, const float* __restrict__ zx,
                            const float* __restrict__ yyw, const float* __restrict__ yyb,
                            const float* __restrict__ xyw, const float* __restrict__ xyb,
                            const float* __restrict__ ayw, const float* __restrict__ ayb,
                            const float* __restrict__ w1, const float* __restrict__ b1,
                            const float* __restrict__ w2, const float* __restrict__ b2,
                            float* __restrict__ out) {
    const int b = blockIdx.x;
    const int tid = threadIdx.x;
    const int o = tid & 127;
    const int q = tid >> 7;
    __shared__ float zy[1664];           // [y(128) | za(512) | zx(1024)]
    for (int idx = tid; idx < 1664; idx += 512) {
        float v;
        if (idx < 128)      v = y[b * YD + idx];
        else if (idx < 640) v = za[b * 512 + idx - 128];
        else                v = zx[b * 1024 + idx - 640];
        zy[idx] = v;
    }
    __syncthreads();
    float p = 0.f;
    if (q == 0) {
        for (int k = 0; k < 128; ++k) p += zy[k] * yyw[k * YD + o];
        for (int k = 0; k < 128; ++k) p += zy[128 + k] * ayw[k * YD + o];
    } else if (q == 1) {
        for (int k = 128; k < 512; ++k) p += zy[128 + k] * ayw[k * YD + o];
    } else if (q == 2) {
        for (int k = 0; k < 512; ++k) p += zy[640 + k] * xyw[k * YD + o];
    } else {
        for (int k = 512; k < 1024; ++k) p += zy[640 + k] * xyw[k * YD + o];
    }
    __shared__ float red[4][128];
    __shared__ float h1s[128], h2s[128];
    red[q][o] = p;
    __syncthreads();
    if (tid < 128) {
        h1s[o] = yyb[o] + xyb[o] + ayb[o] + red[0][o] + red[1][o] + red[2][o] + red[3][o];
    }
    __syncthreads();
    float p2 = 0.f;
    for (int k = q * 32; k < q * 32 + 32; ++k) p2 += h1s[k] * w1[k * YD + o];
    red[q][o] = p2;
    __syncthreads();
    if (tid < 128) h2s[o] = fmaxf(b1[o] + red[0][o] + red[1][o] + red[2][o] + red[3][o], 0.f);
    __syncthreads();
    float p3 = 0.f;
    for (int k = q * 32; k < q * 32 + 32; ++k) p3 += h2s[k] * w2[k * YD + o];
    red[q][o] = p3;
    __syncthreads();
    if (tid < 128) out[b * YD + o] = b2[o] + red[0][o] + red[1][o] + red[2][o] + red[3][o];
}

// ---------------------------------------------------------------------------
extern "C" void kernel_launch(void* const* d_in, const int* in_sizes, int n_in,
                              void* d_out, int out_size, void* d_ws, size_t ws_size,
                              hipStream_t stream) {
    const float* x         = (const float*)d_in[0];
    const float* a         = (const float*)d_in[1];
    const float* y         = (const float*)d_in[2];
    const float* qw        = (const float*)d_in[3];  const float* qb        = (const float*)d_in[4];
    const float* kw        = (const float*)d_in[5];  const float* kb        = (const float*)d_in[6];
    const float* vw        = (const float*)d_in[7];  const float* vb        = (const float*)d_in[8];
    const float* a2x_add_w = (const float*)d_in[9];  const float* a2x_add_b = (const float*)d_in[10];
    const float* a2x_mul_w = (const float*)d_in[11]; const float* a2x_mul_b = (const float*)d_in[12];
    const float* y2e_mul_w = (const float*)d_in[13]; const float* y2e_mul_b = (const float*)d_in[14];
    const float* y2e_add_w = (const float*)d_in[15]; const float* y2e_add_b = (const float*)d_in[16];
    const float* y2x_mul_w = (const float*)d_in[17]; const float* y2x_mul_b = (const float*)d_in[18];
    const float* y2x_add_w = (const float*)d_in[19]; const float* y2x_add_b = (const float*)d_in[20];
    const float* y_y_w     = (const float*)d_in[21]; const float* y_y_b     = (const float*)d_in[22];
    const float* x_y_w     = (const float*)d_in[23]; const float* x_y_b     = (const float*)d_in[24];
    const float* a_y_w     = (const float*)d_in[25]; const float* a_y_b     = (const float*)d_in[26];
    const float* x_out_w   = (const float*)d_in[27]; const float* x_out_b   = (const float*)d_in[28];
    const float* a_out_w   = (const float*)d_in[29]; const float* a_out_b   = (const float*)d_in[30];
    const float* y_out1_w  = (const float*)d_in[31]; const float* y_out1_b  = (const float*)d_in[32];
    const float* y_out2_w  = (const float*)d_in[33]; const float* y_out2_b  = (const float*)d_in[34];

    float* ws = (float*)d_ws;
    float* Q      = ws;                                   // 131072
    unsigned short* kvJ = (unsigned short*)(ws + 131072); // 262144 u16 = 131072 f
    float* wV     = ws + 262144;                          // 131072
    float* ye1    = ws + 393216;   // 512
    float* ye2    = ws + 393728;
    float* yx1    = ws + 394240;
    float* yx2    = ws + 394752;
    float* psum   = ws + 395264;   // 65536
    float* psumsq = ws + 460800;
    float* pminb  = ws + 526336;
    float* pmaxb  = ws + 591872;
    float* za     = ws + 657408;   // 1024
    float* zx     = ws + 658432;   // 2048
    unsigned short* WaddT = (unsigned short*)(ws + 660480);  // 32768 u16
    unsigned short* WmulT = (unsigned short*)(ws + 676864);
    unsigned short* W2T   = (unsigned short*)(ws + 693248);

    float* xhat = (float*)d_out;
    float* ahat = (float*)d_out + 131072;
    float* yhat = (float*)d_out + 16908288;

    wt_kernel<<<384, 256, 0, stream>>>(a2x_add_w, a2x_mul_w, a_out_w, WaddT, WmulT, W2T);
    qkv_kernel<<<192, 256, 0, stream>>>(x, qw, qb, kw, kb, vw, vb, Q, kvJ);
    ymap_kernel<<<8, 256, 0, stream>>>(y, y2e_add_w, y2e_add_b, y2e_mul_w, y2e_mul_b,
                                       y2x_add_w, y2x_add_b, y2x_mul_w, y2x_mul_b,
                                       ye1, ye2, yx1, yx2);
    za_part_kernel<<<512, 128, 0, stream>>>(a, psum, psumsq, pminb, pmaxb);
    zx_kernel<<<2, 256, 0, stream>>>(x, zx);
    main_kernel<<<512, 512, 0, stream>>>(a, WaddT, a2x_add_b, WmulT, a2x_mul_b,
                                         W2T, a_out_b, Q, kvJ, ye1, ye2, ahat, wV);
    xhat_kernel<<<64, 256, 0, stream>>>(wV, yx1, yx2, x_out_w, x_out_b, xhat);
    za_reduce_kernel<<<2, 512, 0, stream>>>(psum, psumsq, pminb, pmaxb, za);
    yhat_kernel<<<2, 512, 0, stream>>>(y, za, zx, y_y_w, y_y_b, x_y_w, x_y_b, a_y_w, a_y_b,
                                       y_out1_w, y_out1_b, y_out2_w, y_out2_b, yhat);
}

// Round 6
// 155.507 us; speedup vs baseline: 4.2419x; 1.1699x over previous
//
#include <hip/hip_runtime.h>
#include <hip/hip_bf16.h>
#include <cstddef>

// Problem constants
constexpr int BS = 2;
constexpr int N  = 256;
constexpr int D  = 256;   // NH_N
constexpr int E  = 128;   // NH_E
constexpr int YD = 128;   // NH_Y
constexpr float RSQRT_F = 0.17677669529663687f;  // 1/sqrt(32)

typedef __attribute__((ext_vector_type(8))) short     short8;
typedef __attribute__((ext_vector_type(4))) float     f32x4;
typedef __attribute__((ext_vector_type(4))) unsigned short u16x4;
typedef __attribute__((ext_vector_type(8))) unsigned short u16x8;

__device__ __forceinline__ unsigned short f2bf(float x) {
    unsigned u = __float_as_uint(x);
    unsigned r = (u + 0x7fffu + ((u >> 16) & 1u)) >> 16;   // RNE
    return (unsigned short)r;
}
__device__ __forceinline__ float bf2f(unsigned short h) {
    return __uint_as_float(((unsigned)h) << 16);
}
__device__ __forceinline__ f32x4 mfma16(short8 a, short8 b, f32x4 c) {
    return __builtin_amdgcn_mfma_f32_16x16x32_bf16(a, b, c, 0, 0, 0);
}

// ---------------------------------------------------------------------------
// prep: transpose + bf16-convert the three big weight matrices
// ---------------------------------------------------------------------------
__global__ void wt_kernel(const float* __restrict__ Wadd, const float* __restrict__ Wmul,
                          const float* __restrict__ W2,
                          unsigned short* __restrict__ WaddT, unsigned short* __restrict__ WmulT,
                          unsigned short* __restrict__ W2T) {
    int idx = blockIdx.x * 256 + threadIdx.x;
    int s = idx >> 15;          // 32768 per section
    int k = idx & 32767;
    if (s == 0)      { int f = k >> 7, e = k & 127; WaddT[k] = f2bf(Wadd[e * 256 + f]); }
    else if (s == 1) { int f = k >> 7, e = k & 127; WmulT[k] = f2bf(Wmul[e * 256 + f]); }
    else             { int f = k & 255, e = k >> 8; W2T[k]   = f2bf(W2[f * 128 + e]); }
}

// ---------------------------------------------------------------------------
// K1: Q = x@qw+qb (fp32, row-major); K/V -> kvJ bf16 row-major interleaved:
// kvJ u16 layout: ((b*256 + j)*256 + f)*2 + {0:K,1:V}
// ---------------------------------------------------------------------------
__global__ void qkv_kernel(const float* __restrict__ x,
                           const float* __restrict__ qw, const float* __restrict__ qb,
                           const float* __restrict__ kw, const float* __restrict__ kb,
                           const float* __restrict__ vw, const float* __restrict__ vb,
                           float* __restrict__ Q, unsigned short* __restrict__ kvJ) {
    const int m  = blockIdx.x >> 6;
    const int rg = blockIdx.x & 63;
    const float* W = (m == 0) ? qw : (m == 1) ? kw : vw;
    const float* B = (m == 0) ? qb : (m == 1) ? kb : vb;

    __shared__ float xs[8][D];
    const int tid = threadIdx.x;
#pragma unroll
    for (int r = 0; r < 8; ++r)
        xs[r][tid] = x[(size_t)(rg * 8 + r) * D + tid];
    __syncthreads();

    float acc[8];
    const float bb = B[tid];
#pragma unroll
    for (int r = 0; r < 8; ++r) acc[r] = bb;
    for (int k = 0; k < D; ++k) {
        const float w = W[k * D + tid];
#pragma unroll
        for (int r = 0; r < 8; ++r) acc[r] += xs[r][k] * w;
    }
#pragma unroll
    for (int r = 0; r < 8; ++r) {
        const int row = rg * 8 + r;
        if (m == 0) Q[(size_t)row * D + tid] = acc[r];
        else        kvJ[((size_t)row * D + tid) * 2 + (m - 1)] = f2bf(acc[r]);
    }
}

// ---------------------------------------------------------------------------
// ymap
// ---------------------------------------------------------------------------
__global__ void ymap_kernel(const float* __restrict__ y,
                            const float* __restrict__ we_add, const float* __restrict__ be_add,
                            const float* __restrict__ we_mul, const float* __restrict__ be_mul,
                            const float* __restrict__ wx_add, const float* __restrict__ bx_add,
                            const float* __restrict__ wx_mul, const float* __restrict__ bx_mul,
                            float* __restrict__ ye1, float* __restrict__ ye2,
                            float* __restrict__ yx1, float* __restrict__ yx2) {
    const int b = blockIdx.x >> 2;
    const int m = blockIdx.x & 3;
    const int f = threadIdx.x;
    const float* W; const float* B; float* O;
    switch (m) {
        case 0:  W = we_add; B = be_add; O = ye1; break;
        case 1:  W = we_mul; B = be_mul; O = ye2; break;
        case 2:  W = wx_add; B = bx_add; O = yx1; break;
        default: W = wx_mul; B = bx_mul; O = yx2; break;
    }
    float acc = B[f];
    for (int k = 0; k < YD; ++k)
        acc += y[b * YD + k] * W[k * D + f];
    O[b * D + f] = acc;
}

// ---------------------------------------------------------------------------
// za partial stats: 512 thr, 4-way j-split + LDS reduce (shorter latency chains)
// ---------------------------------------------------------------------------
__global__ void za_part_kernel(const float* __restrict__ a,
                               float* __restrict__ psum, float* __restrict__ psumsq,
                               float* __restrict__ pmin, float* __restrict__ pmax) {
    const int blk  = blockIdx.x;
    const int tid  = threadIdx.x;
    const int feat = tid & 127;
    const int g    = tid >> 7;          // 0..3
    const float* base = a + (size_t)blk * 256 * E + feat;
    float s = 0.f, ss = 0.f, mn = INFINITY, mx = -INFINITY;
    for (int r = g * 64; r < g * 64 + 64; ++r) {
        const float v = base[(size_t)r * E];
        s += v; ss += v * v; mn = fminf(mn, v); mx = fmaxf(mx, v);
    }
    __shared__ float rs[4][128], rss[4][128], rmn[4][128], rmx[4][128];
    rs[g][feat] = s; rss[g][feat] = ss; rmn[g][feat] = mn; rmx[g][feat] = mx;
    __syncthreads();
    if (g == 0) {
#pragma unroll
        for (int gg = 1; gg < 4; ++gg) {
            s += rs[gg][feat]; ss += rss[gg][feat];
            mn = fminf(mn, rmn[gg][feat]); mx = fmaxf(mx, rmx[gg][feat]);
        }
        const int o = blk * E + feat;
        psum[o] = s; psumsq[o] = ss; pmin[o] = mn; pmax[o] = mx;
    }
}

// grid 2, block 1024: 8-way k-split + LDS reduce
__global__ void za_reduce_kernel(const float* __restrict__ psum, const float* __restrict__ psumsq,
                                 const float* __restrict__ pmin, const float* __restrict__ pmax,
                                 float* __restrict__ za) {
    const int b = blockIdx.x;
    const int feat = threadIdx.x & 127;
    const int g = threadIdx.x >> 7;      // 0..7
    float s = 0.f, ss = 0.f, mn = INFINITY, mx = -INFINITY;
    for (int c = g * 32; c < g * 32 + 32; ++c) {
        const int o = (b * 256 + c) * E + feat;
        s += psum[o]; ss += psumsq[o];
        mn = fminf(mn, pmin[o]); mx = fmaxf(mx, pmax[o]);
    }
    __shared__ float rs[8][128], rss[8][128], rmn[8][128], rmx[8][128];
    rs[g][feat] = s; rss[g][feat] = ss; rmn[g][feat] = mn; rmx[g][feat] = mx;
    __syncthreads();
    if (g == 0) {
#pragma unroll
        for (int gg = 1; gg < 8; ++gg) {
            s += rs[gg][feat]; ss += rss[gg][feat];
            mn = fminf(mn, rmn[gg][feat]); mx = fmaxf(mx, rmx[gg][feat]);
        }
        const float M = 65536.f;
        const float mean = s / M;
        const float var  = (ss - s * s / M) / (M - 1.f);
        za[b * 512 + feat]       = mean;
        za[b * 512 + 128 + feat] = mn;
        za[b * 512 + 256 + feat] = mx;
        za[b * 512 + 384 + feat] = sqrtf(fmaxf(var, 0.f));
    }
}

// grid 16 (2 b x 8 f-chunks), block 256 (32 f x 8 i-groups)
__global__ void zx_kernel(const float* __restrict__ x, float* __restrict__ zx) {
    const int b  = blockIdx.x >> 3;
    const int fc = blockIdx.x & 7;
    const int fl = threadIdx.x & 31;
    const int ig = threadIdx.x >> 5;     // 0..7
    const int f  = fc * 32 + fl;
    float s = 0.f, ss = 0.f, mn = INFINITY, mx = -INFINITY;
    for (int i = ig * 32; i < ig * 32 + 32; ++i) {
        const float v = x[((size_t)b * N + i) * D + f];
        s += v; ss += v * v; mn = fminf(mn, v); mx = fmaxf(mx, v);
    }
    __shared__ float rs[8][32], rss[8][32], rmn[8][32], rmx[8][32];
    rs[ig][fl] = s; rss[ig][fl] = ss; rmn[ig][fl] = mn; rmx[ig][fl] = mx;
    __syncthreads();
    if (ig == 0) {
#pragma unroll
        for (int gg = 1; gg < 8; ++gg) {
            s += rs[gg][fl]; ss += rss[gg][fl];
            mn = fminf(mn, rmn[gg][fl]); mx = fmaxf(mx, rmx[gg][fl]);
        }
        const float M = 256.f;
        const float mean = s / M;
        const float var  = (ss - s * s / M) / (M - 1.f);
        zx[b * 1024 + f]       = mean;
        zx[b * 1024 + 256 + f] = mn;
        zx[b * 1024 + 512 + f] = mx;
        zx[b * 1024 + 768 + f] = sqrtf(fmaxf(var, 0.f));
    }
}

// ---------------------------------------------------------------------------
// MAIN: block = one (b,i). 8 waves; wave w owns f-block [w*32, w*32+32).
// 8 passes x 32 j. ALL weight fragments (Wadd/Wmul/W2 slices, 24 short8 =
// 96 VGPR) hoisted into registers once per block -> GEMM loops are pure
// LDS+MFMA. __launch_bounds__(512,1): 256-VGPR budget, 1 block/CU.
// ---------------------------------------------------------------------------
__global__ __launch_bounds__(512, 1) void main_kernel(
        const float* __restrict__ a,
        const unsigned short* __restrict__ WaddT, const float* __restrict__ Badd,
        const unsigned short* __restrict__ WmulT, const float* __restrict__ Bmul,
        const unsigned short* __restrict__ W2T,  const float* __restrict__ AoutB,
        const float* __restrict__ Q, const unsigned short* __restrict__ kvJ,
        const float* __restrict__ ye1, const float* __restrict__ ye2,
        float* __restrict__ ahat, float* __restrict__ wV) {
    const int bi = blockIdx.x;         // b*256 + i
    const int b  = bi >> 8;
    const int tid  = threadIdx.x;
    const int lane = tid & 63;
    const int w    = tid >> 6;         // wave id 0..7
    const int l15  = lane & 15;
    const int lk   = lane >> 4;        // 0..3

    __shared__ unsigned short abuf[2][32 * 128];   // 2 x 8 KB  a-tile bf16 (swizzled)
    __shared__ unsigned short hbuf[2][32 * 256];   // 2 x 16 KB h bf16 (swizzled)

    const float* arow = a + (size_t)bi * (N * E);
    float* ahatp      = ahat + (size_t)bi * (N * E);
    const unsigned short* kvb = kvJ + (size_t)b * N * D * 2;

    // ---- hoist ALL weight fragments (pass-invariant) into registers ----
    short8 waf[4][2], wmf[4][2], w2f[8];
#pragma unroll
    for (int ks = 0; ks < 4; ++ks)
#pragma unroll
        for (int m_ = 0; m_ < 2; ++m_) {
            const int frow = w * 32 + m_ * 16 + l15;
            waf[ks][m_] = *(const short8*)(WaddT + frow * 128 + ks * 32 + lk * 8);
            wmf[ks][m_] = *(const short8*)(WmulT + frow * 128 + ks * 32 + lk * 8);
        }
#pragma unroll
    for (int ks = 0; ks < 8; ++ks)
        w2f[ks] = *(const short8*)(W2T + (w * 16 + l15) * 256 + ks * 32 + lk * 8);

    // hoisted per-f constants: f = w*32 + m_*16 + lk*4 + r  (fi = m_*4+r)
    float qs[8], e1c[8], e2c[8], b1c[8], b2c[8];
#pragma unroll
    for (int m_ = 0; m_ < 2; ++m_) {
        const int f0 = w * 32 + m_ * 16 + lk * 4;
        const f32x4 qv = *(const f32x4*)(Q + (size_t)bi * D + f0);
        const f32x4 a1 = *(const f32x4*)(ye1 + b * D + f0);
        const f32x4 a2 = *(const f32x4*)(ye2 + b * D + f0);
        const f32x4 bb1 = *(const f32x4*)(Badd + f0);
        const f32x4 bb2 = *(const f32x4*)(Bmul + f0);
#pragma unroll
        for (int r = 0; r < 4; ++r) {
            const int fi = m_ * 4 + r;
            qs[fi]  = qv[r] * RSQRT_F;
            e1c[fi] = a1[r];
            e2c[fi] = a2[r] + 1.f;
            b1c[fi] = bb1[r] + 1.f;   // (a1 + 1) bias
            b2c[fi] = bb2[r];
        }
    }
    const f32x4 bias2 = *(const f32x4*)(AoutB + w * 16 + lk * 4);

    // softmax accumulators (no max tracking: |Y| <~ 2.5 by construction)
    float sm_l[8], sm_a[8];
#pragma unroll
    for (int q = 0; q < 8; ++q) { sm_l[q] = 0.f; sm_a[q] = 0.f; }

    const int sjl = tid >> 4;          // staging row 0..31
    const int seq = tid & 15;          // staging 8-float chunk
    const unsigned saddr = ((unsigned)(sjl * 256 + seq * 16)) ^ ((unsigned)(sjl & 7) << 4);

    // prologue: stage pass 0
    {
        const float* ap = arow + (size_t)sjl * E + seq * 8;
        const f32x4 v0 = *(const f32x4*)ap;
        const f32x4 v1 = *(const f32x4*)(ap + 4);
        u16x8 pk;
        pk.s0 = f2bf(v0.x); pk.s1 = f2bf(v0.y); pk.s2 = f2bf(v0.z); pk.s3 = f2bf(v0.w);
        pk.s4 = f2bf(v1.x); pk.s5 = f2bf(v1.y); pk.s6 = f2bf(v1.z); pk.s7 = f2bf(v1.w);
        *(u16x8*)((char*)abuf[0] + saddr) = pk;
    }
    __syncthreads();

    for (int t = 0; t < 8; ++t) {
        const int j0 = t * 32;
        const unsigned short* ab = abuf[t & 1];
        unsigned short* hw = hbuf[t & 1];

        // issue global prefetches early: next a-tile (HBM) + this pass's kv (L2)
        f32x4 p0, p1;
        if (t < 7) {
            const float* ap = arow + (size_t)(j0 + 32 + sjl) * E + seq * 8;
            p0 = *(const f32x4*)ap;
            p1 = *(const f32x4*)(ap + 4);
        }
        u16x8 kvv[2][2];
#pragma unroll
        for (int n_ = 0; n_ < 2; ++n_) {
            const int jg = j0 + n_ * 16 + l15;
#pragma unroll
            for (int m_ = 0; m_ < 2; ++m_)
                kvv[n_][m_] = *(const u16x8*)(kvb + ((size_t)jg * D + w * 32 + m_ * 16 + lk * 4) * 2);
        }

        // ---- GEMM1 (weights in regs): acc[m_][n_] over both 16-j halves ----
        f32x4 acc1[2][2], acc2[2][2];
#pragma unroll
        for (int m_ = 0; m_ < 2; ++m_) {
            const f32x4 i1 = (f32x4){b1c[m_ * 4 + 0], b1c[m_ * 4 + 1], b1c[m_ * 4 + 2], b1c[m_ * 4 + 3]};
            const f32x4 i2 = (f32x4){b2c[m_ * 4 + 0], b2c[m_ * 4 + 1], b2c[m_ * 4 + 2], b2c[m_ * 4 + 3]};
#pragma unroll
            for (int n_ = 0; n_ < 2; ++n_) { acc1[m_][n_] = i1; acc2[m_][n_] = i2; }
        }
#pragma unroll
        for (int ks = 0; ks < 4; ++ks) {
            short8 bfrg[2];
#pragma unroll
            for (int n_ = 0; n_ < 2; ++n_) {
                const int jrow = n_ * 16 + l15;
                const unsigned baddr = ((unsigned)(jrow * 256 + (ks * 32 + lk * 8) * 2))
                                       ^ ((unsigned)(jrow & 7) << 4);
                bfrg[n_] = *(const short8*)((const char*)ab + baddr);
            }
#pragma unroll
            for (int m_ = 0; m_ < 2; ++m_)
#pragma unroll
                for (int n_ = 0; n_ < 2; ++n_) {
                    acc1[m_][n_] = mfma16(waf[ks][m_], bfrg[n_], acc1[m_][n_]);
                    acc2[m_][n_] = mfma16(wmf[ks][m_], bfrg[n_], acc2[m_][n_]);
                }
        }

        // ---- phase B (in-register): Y, h->LDS, softmax accumulation ----
#pragma unroll
        for (int n_ = 0; n_ < 2; ++n_) {
            const int jrow = n_ * 16 + l15;
#pragma unroll
            for (int m_ = 0; m_ < 2; ++m_) {
                u16x4 hp;
#pragma unroll
                for (int r = 0; r < 4; ++r) {
                    const int fi = m_ * 4 + r;
                    const float kf = bf2f(kvv[n_][m_][2 * r]);
                    const float vf = bf2f(kvv[n_][m_][2 * r + 1]);
                    const float yv = qs[fi] * kf * acc1[m_][n_][r] + acc2[m_][n_][r];
                    hp[r] = f2bf(e1c[fi] + e2c[fi] * yv);
                    const float ev = __expf(yv);
                    sm_l[fi] += ev;
                    sm_a[fi] += ev * vf;
                }
                const unsigned haddr = ((unsigned)(jrow * 512 + (w * 32 + m_ * 16 + lk * 4) * 2))
                                       ^ ((unsigned)(jrow & 7) << 4);
                *(u16x4*)((char*)hw + haddr) = hp;
            }
        }

        // ---- write prefetched a-tile to the other buffer ----
        if (t < 7) {
            u16x8 pk;
            pk.s0 = f2bf(p0.x); pk.s1 = f2bf(p0.y); pk.s2 = f2bf(p0.z); pk.s3 = f2bf(p0.w);
            pk.s4 = f2bf(p1.x); pk.s5 = f2bf(p1.y); pk.s6 = f2bf(p1.z); pk.s7 = f2bf(p1.w);
            *(u16x8*)((char*)abuf[(t + 1) & 1] + saddr) = pk;
        }
        __syncthreads();   // h ready; next a-tile ready; abuf[t&1] reads done

        // ---- GEMM2 (weights in regs): ahat^T[e][j] = W2T . h^T (+bias) ----
        f32x4 accO[2];
        accO[0] = bias2; accO[1] = bias2;
#pragma unroll
        for (int ks = 0; ks < 8; ++ks) {
            const int foff = ks * 32 + lk * 8;
#pragma unroll
            for (int n2 = 0; n2 < 2; ++n2) {
                const int jrow = n2 * 16 + l15;
                const unsigned haddr = ((unsigned)(jrow * 512 + foff * 2))
                                       ^ ((unsigned)(jrow & 7) << 4);
                const short8 hf = *(const short8*)((const char*)hw + haddr);
                accO[n2] = mfma16(w2f[ks], hf, accO[n2]);
            }
        }
        {
            const int eb = w * 16 + lk * 4;
#pragma unroll
            for (int n2 = 0; n2 < 2; ++n2) {
                const int jg2 = j0 + n2 * 16 + l15;
                *(f32x4*)(ahatp + (size_t)jg2 * E + eb) = accO[n2];
            }
        }
    }

    // ---- merge softmax partials across l15 (sum over j-columns) ----
#pragma unroll
    for (int st = 1; st <= 8; st <<= 1) {
#pragma unroll
        for (int fi = 0; fi < 8; ++fi) {
            sm_l[fi] += __shfl_xor(sm_l[fi], st, 64);
            sm_a[fi] += __shfl_xor(sm_a[fi], st, 64);
        }
    }
    if (l15 == 0) {
#pragma unroll
        for (int m_ = 0; m_ < 2; ++m_)
#pragma unroll
            for (int r = 0; r < 4; ++r) {
                const int fi = m_ * 4 + r;
                const int f  = w * 32 + m_ * 16 + lk * 4 + r;
                wV[(size_t)bi * D + f] = sm_a[fi] / sm_l[fi];
            }
    }
}

// ---------------------------------------------------------------------------
// xhat = (yx1 + (yx2+1)*wV) @ x_out_w + x_out_b
// ---------------------------------------------------------------------------
__global__ void xhat_kernel(const float* __restrict__ wV,
                            const float* __restrict__ yx1, const float* __restrict__ yx2,
                            const float* __restrict__ W, const float* __restrict__ B,
                            float* __restrict__ out) {
    const int rg = blockIdx.x;
    const int tid = threadIdx.x;
    __shared__ float xr[8][D];
#pragma unroll
    for (int r = 0; r < 8; ++r) {
        const int row = rg * 8 + r;
        const int b = row >> 8;
        xr[r][tid] = yx1[b * D + tid] + (yx2[b * D + tid] + 1.f) * wV[(size_t)row * D + tid];
    }
    __syncthreads();
    float acc[8];
    const float bb = B[tid];
#pragma unroll
    for (int r = 0; r < 8; ++r) acc[r] = bb;
    for (int k = 0; k < D; ++k) {
        const float w = W[k * D + tid];
#pragma unroll
        for (int r = 0; r < 8; ++r) acc[r] += xr[r][k] * w;
    }
#pragma unroll
    for (int r = 0; r < 8; ++r)
        out[(size_t)(rg * 8 + r) * D + tid] = acc[r];
}

// ---------------------------------------------------------------------------
// yhat MLP — 512 threads, 4-way k-split + LDS reduce
// ---------------------------------------------------------------------------
__global__ void yhat_kernel(const float* __restrict__ y,
                            const float* __restrict__ za, const float* __restrict__ zx,
                            const float* __restrict__ yyw, const float* __restrict__ yyb,
                            const float* __restrict__ xyw, const float* __restrict__ xyb,
                            const float* __restrict__ ayw, const float* __restrict__ ayb,
                            const float* __restrict__ w1, const float* __restrict__ b1,
                            const float* __restrict__ w2, const float* __restrict__ b2,
                            float* __restrict__ out) {
    const int b = blockIdx.x;
    const int tid = threadIdx.x;
    const int o = tid & 127;
    const int q = tid >> 7;
    __shared__ float zy[1664];           // [y(128) | za(512) | zx(1024)]
    for (int idx = tid; idx < 1664; idx += 512) {
        float v;
        if (idx < 128)      v = y[b * YD + idx];
        else if (idx < 640) v = za[b * 512 + idx - 128];
        else                v = zx[b * 1024 + idx - 640];
        zy[idx] = v;
    }
    __syncthreads();
    float p = 0.f;
    if (q == 0) {
        for (int k = 0; k < 128; ++k) p += zy[k] * yyw[k * YD + o];
        for (int k = 0; k < 128; ++k) p += zy[128 + k] * ayw[k * YD + o];
    } else if (q == 1) {
        for (int k = 128; k < 512; ++k) p += zy[128 + k] * ayw[k * YD + o];
    } else if (q == 2) {
        for (int k = 0; k < 512; ++k) p += zy[640 + k] * xyw[k * YD + o];
    } else {
        for (int k = 512; k < 1024; ++k) p += zy[640 + k] * xyw[k * YD + o];
    }
    __shared__ float red[4][128];
    __shared__ float h1s[128], h2s[128];
    red[q][o] = p;
    __syncthreads();
    if (tid < 128) {
        h1s[o] = yyb[o] + xyb[o] + ayb[o] + red[0][o] + red[1][o] + red[2][o] + red[3][o];
    }
    __syncthreads();
    float p2 = 0.f;
    for (int k = q * 32; k < q * 32 + 32; ++k) p2 += h1s[k] * w1[k * YD + o];
    red[q][o] = p2;
    __syncthreads();
    if (tid < 128) h2s[o] = fmaxf(b1[o] + red[0][o] + red[1][o] + red[2][o] + red[3][o], 0.f);
    __syncthreads();
    float p3 = 0.f;
    for (int k = q * 32; k < q * 32 + 32; ++k) p3 += h2s[k] * w2[k * YD + o];
    red[q][o] = p3;
    __syncthreads();
    if (tid < 128) out[b * YD + o] = b2[o] + red[0][o] + red[1][o] + red[2][o] + red[3][o];
}

// ---------------------------------------------------------------------------
extern "C" void kernel_launch(void* const* d_in, const int* in_sizes, int n_in,
                              void* d_out, int out_size, void* d_ws, size_t ws_size,
                              hipStream_t stream) {
    const float* x         = (const float*)d_in[0];
    const float* a         = (const float*)d_in[1];
    const float* y         = (const float*)d_in[2];
    const float* qw        = (const float*)d_in[3];  const float* qb        = (const float*)d_in[4];
    const float* kw        = (const float*)d_in[5];  const float* kb        = (const float*)d_in[6];
    const float* vw        = (const float*)d_in[7];  const float* vb        = (const float*)d_in[8];
    const float* a2x_add_w = (const float*)d_in[9];  const float* a2x_add_b = (const float*)d_in[10];
    const float* a2x_mul_w = (const float*)d_in[11]; const float* a2x_mul_b = (const float*)d_in[12];
    const float* y2e_mul_w = (const float*)d_in[13]; const float* y2e_mul_b = (const float*)d_in[14];
    const float* y2e_add_w = (const float*)d_in[15]; const float* y2e_add_b = (const float*)d_in[16];
    const float* y2x_mul_w = (const float*)d_in[17]; const float* y2x_mul_b = (const float*)d_in[18];
    const float* y2x_add_w = (const float*)d_in[19]; const float* y2x_add_b = (const float*)d_in[20];
    const float* y_y_w     = (const float*)d_in[21]; const float* y_y_b     = (const float*)d_in[22];
    const float* x_y_w     = (const float*)d_in[23]; const float* x_y_b     = (const float*)d_in[24];
    const float* a_y_w     = (const float*)d_in[25]; const float* a_y_b     = (const float*)d_in[26];
    const float* x_out_w   = (const float*)d_in[27]; const float* x_out_b   = (const float*)d_in[28];
    const float* a_out_w   = (const float*)d_in[29]; const float* a_out_b   = (const float*)d_in[30];
    const float* y_out1_w  = (const float*)d_in[31]; const float* y_out1_b  = (const float*)d_in[32];
    const float* y_out2_w  = (const float*)d_in[33]; const float* y_out2_b  = (const float*)d_in[34];

    float* ws = (float*)d_ws;
    float* Q      = ws;                                   // 131072
    unsigned short* kvJ = (unsigned short*)(ws + 131072); // 262144 u16 = 131072 f
    float* wV     = ws + 262144;                          // 131072
    float* ye1    = ws + 393216;   // 512
    float* ye2    = ws + 393728;
    float* yx1    = ws + 394240;
    float* yx2    = ws + 394752;
    float* psum   = ws + 395264;   // 65536
    float* psumsq = ws + 460800;
    float* pminb  = ws + 526336;
    float* pmaxb  = ws + 591872;
    float* za     = ws + 657408;   // 1024
    float* zx     = ws + 658432;   // 2048
    unsigned short* WaddT = (unsigned short*)(ws + 660480);  // 32768 u16
    unsigned short* WmulT = (unsigned short*)(ws + 676864);
    unsigned short* W2T   = (unsigned short*)(ws + 693248);

    float* xhat = (float*)d_out;
    float* ahat = (float*)d_out + 131072;
    float* yhat = (float*)d_out + 16908288;

    wt_kernel<<<384, 256, 0, stream>>>(a2x_add_w, a2x_mul_w, a_out_w, WaddT, WmulT, W2T);
    qkv_kernel<<<192, 256, 0, stream>>>(x, qw, qb, kw, kb, vw, vb, Q, kvJ);
    ymap_kernel<<<8, 256, 0, stream>>>(y, y2e_add_w, y2e_add_b, y2e_mul_w, y2e_mul_b,
                                       y2x_add_w, y2x_add_b, y2x_mul_w, y2x_mul_b,
                                       ye1, ye2, yx1, yx2);
    za_part_kernel<<<512, 512, 0, stream>>>(a, psum, psumsq, pminb, pmaxb);
    zx_kernel<<<16, 256, 0, stream>>>(x, zx);
    main_kernel<<<512, 512, 0, stream>>>(a, WaddT, a2x_add_b, WmulT, a2x_mul_b,
                                         W2T, a_out_b, Q, kvJ, ye1, ye2, ahat, wV);
    xhat_kernel<<<64, 256, 0, stream>>>(wV, yx1, yx2, x_out_w, x_out_b, xhat);
    za_reduce_kernel<<<2, 1024, 0, stream>>>(psum, psumsq, pminb, pmaxb, za);
    yhat_kernel<<<2, 512, 0, stream>>>(y, za, zx, y_y_w, y_y_b, x_y_w, x_y_b, a_y_w, a_y_b,
                                       y_out1_w, y_out1_b, y_out2_w, y_out2_b, yhat);
}